// Round 11
// baseline (3894.619 us; speedup 1.0000x reference)
//
#include <hip/hip_runtime.h>
#include <math.h>

#define N_PTS       40000
#define N_ANCH      4000     // ceil(0.1 * 40000)
#define KNN         20
#define NFB         128      // fps blocks (1 wave each)
#define BT          64       // threads per block (all blocks) = 1 wave
#define NWAVES      128                // fps waves
#define STRIDE      (NWAVES * 64)      // 8192 = 2^13
#define PPT         5                  // 8192*5 = 40960 >= 40000
#define TW          8                  // published candidates per WAVE (deep bound: B~85, R8-measured)
#define POOL        (NWAVES * TW)      // 1024
#define RSLOTS      (POOL / 64)        // 16 readback entries per lane
#define CCAP        14                 // compacted capacity/lane (896 = 7/wave x 128, tight)

typedef unsigned long long ull;

#define LD_RLX(p)    __hip_atomic_load((p),  __ATOMIC_RELAXED, __HIP_MEMORY_SCOPE_AGENT)
#define ST_REL(p,v)  __hip_atomic_store((p), (v), __ATOMIC_RELEASE, __HIP_MEMORY_SCOPE_AGENT)
#define ST_RLX(p,v)  __hip_atomic_store((p), (v), __ATOMIC_RELAXED, __HIP_MEMORY_SCOPE_AGENT)

// Workspace layout:
//   off     0 : double acc               (zeroed)
//   off    64 : int flag[128]            (zeroed; per-wave monotone batch counters)
//   off  1024 : ull slots[2][1024]       (parity x pool, packed {key32|idx16}; 16 KB)
//   off 17408 : int anchors[4000]        (memset 0xFF -> -1)
//
// R10 post-mortem: alpha (per-selection) is now ~0.2us after the f32 +
// zero-crosslane chain; the dominant term is B*C = 194 batches x ~8-9us sync.
// This round cuts B via the TW=8 deep bound (B~85, measured R8) -- affordable
// NOW because the CCAP=14 cost that sank R8 (f64, branchless, 14 always-hot
// slots) collapsed to f32-guarded with only ~3-5 ACTIVE slots per selection.

__device__ __forceinline__ float dist32(float px, float py, float pz,
                                        float wx, float wy, float wz) {
  float dx = px - wx, dy = py - wy, dz = pz - wz;
  return dx * dx + dy * dy + dz * dz;
}

// monotone u32 key from f32 (exact order embedding)
__device__ __forceinline__ unsigned key32f(float v) {
  unsigned b = __float_as_uint(v);
  return (b & 0x80000000u) ? ~b : (b | 0x80000000u);
}

// published slot: (value-desc, idx-asc) as ONE u64.
__device__ __forceinline__ ull pack_key32(unsigned key, int idx) {
  return ((ull)key << 32) | (ull)((0xFFFF - idx) & 0xFFFF);
}

// wave-wide max of u32 via DPP (VALU only); returns wave-uniform max
__device__ __forceinline__ unsigned wave_umax_dpp(unsigned x) {
#define DPP_STEP(ctrl) { unsigned y = (unsigned)__builtin_amdgcn_update_dpp( \
      0, (int)x, ctrl, 0xf, 0xf, true); x = (y > x) ? y : x; }
  DPP_STEP(0x111)  // row_shr:1
  DPP_STEP(0x112)  // row_shr:2
  DPP_STEP(0x114)  // row_shr:4
  DPP_STEP(0x118)  // row_shr:8
  DPP_STEP(0x142)  // row_bcast:15
  DPP_STEP(0x143)  // row_bcast:31
#undef DPP_STEP
  return (unsigned)__builtin_amdgcn_readlane((int)x, 63);
}

struct FpsSm {                 // single-wave compaction buffers (17920 B)
  ull    lv[CCAP * 64];        // packed keys (with rank in low 16)
  float  lc[CCAP * 64][3];     // coords indexed by rank
};
struct KnnSm { int w[KNN]; };
union Smem { FpsSm f; KnnSm k; };

// ============== symmetric 3x3: eigenvector of largest eigenvalue ===========
__device__ static inline void eig3_maxvec(double xx, double xy, double xz,
                                          double yy, double yz, double zz,
                                          double& v0, double& v1, double& v2) {
  double q  = (xx + yy + zz) / 3.0;
  double p1 = xy * xy + xz * xz + yz * yz;
  double a00 = xx - q, a11 = yy - q, a22 = zz - q;
  double p2 = a00 * a00 + a11 * a11 + a22 * a22 + 2.0 * p1;
  if (p2 < 1e-300) { v0 = 1.0; v1 = 0.0; v2 = 0.0; return; }
  double p   = sqrt(p2 / 6.0);
  double inv = 1.0 / p;
  double b00 = a00 * inv, b01 = xy * inv, b02 = xz * inv;
  double b11 = a11 * inv, b12 = yz * inv, b22 = a22 * inv;
  double detB = b00 * (b11 * b22 - b12 * b12)
              - b01 * (b01 * b22 - b12 * b02)
              + b02 * (b01 * b12 - b11 * b02);
  double r = fmin(1.0, fmax(-1.0, detB * 0.5));
  double phi = acos(r) / 3.0;
  double lam = q + 2.0 * p * cos(phi);   // largest eigenvalue

  double r0x = xx - lam, r0y = xy,       r0z = xz;
  double r1x = xy,       r1y = yy - lam, r1z = yz;
  double r2x = xz,       r2y = yz,       r2z = zz - lam;
  double c0x = r0y * r1z - r0z * r1y, c0y = r0z * r1x - r0x * r1z, c0z = r0x * r1y - r0y * r1x;
  double c1x = r0y * r2z - r0z * r2y, c1y = r0z * r2x - r0x * r2z, c1z = r0x * r2y - r0y * r2x;
  double c2x = r1y * r2z - r1z * r2y, c2y = r1z * r2x - r1x * r2z, c2z = r1x * r2y - r1y * r2x;
  double n0 = c0x * c0x + c0y * c0y + c0z * c0z;
  double n1 = c1x * c1x + c1y * c1y + c1z * c1z;
  double n2 = c2x * c2x + c2y * c2y + c2z * c2z;
  double bx = c0x, by = c0y, bz = c0z, bn = n0;
  if (n1 > bn) { bx = c1x; by = c1y; bz = c1z; bn = n1; }
  if (n2 > bn) { bx = c2x; by = c2y; bz = c2z; bn = n2; }
  if (bn < 1e-280) { v0 = 1.0; v1 = 0.0; v2 = 0.0; return; }
  double s = 1.0 / sqrt(bn);
  v0 = bx * s; v1 = by * s; v2 = bz * s;
}

// ===========================================================================
__global__ __launch_bounds__(BT, 2) void fps_knn_kernel(
    const float* __restrict__ pos, const float* __restrict__ vec_pred,
    int* __restrict__ flag, ull* __restrict__ slots,
    int* __restrict__ anchors, double* __restrict__ acc) {
  __shared__ Smem sm;
  const int lane = threadIdx.x & 63;

  if (blockIdx.x < NFB) {
    // ============ FPS: one wave per block, wave-autonomous ================
    __builtin_amdgcn_s_setprio(1);   // FPS is the critical path (R0: +2-3%)

    const int gw   = blockIdx.x;       // global wave id, 0..127
    const int gtid = gw * 64 + lane;

    float pdx[PPT], pdy[PPT], pdz[PPT], md[PPT];   // f32 coords + min-dist
    const float a0x = pos[0], a0y = pos[1], a0z = pos[2];
#pragma unroll
    for (int k = 0; k < PPT; ++k) {
      int i = gtid + k * STRIDE;
      if (i < N_PTS) {
        pdx[k] = pos[3 * i];
        pdy[k] = pos[3 * i + 1];
        pdz[k] = pos[3 * i + 2];
        md[k]  = dist32(pdx[k], pdy[k], pdz[k], a0x, a0y, a0z);
      } else {
        pdx[k] = 0.0f; pdy[k] = 0.0f; pdz[k] = 0.0f;
        md[k]  = -3.0e38f;   // pad: never beats real md >= 0
      }
    }
    if (gw == 0 && lane == 0) ST_RLX(anchors + 0, 0);

    float bv = -3.3e38f; int bi = 0x7fffffff;
#pragma unroll
    for (int k = 0; k < PPT; ++k) {
      int i = gtid + k * STRIDE;
      bool bt = (md[k] > bv) || (md[k] == bv && i < bi);
      bv = bt ? md[k] : bv; bi = bt ? i : bi;
    }

    int nsel  = 1;
    int batch = 0;
#pragma unroll 1
    while (nsel < N_ANCH) {
      batch++;
      const int par = batch & 1;

      // ---- per-wave top-8 extraction: two-phase DPP, no ballot/readlane ---
      unsigned cons = 0;
      unsigned pkey = 0; int pix = 0;
#pragma unroll 1
      for (int r = 0; r < TW; ++r) {
        unsigned k = key32f(bv);
        unsigned M = wave_umax_dpp(k);
        unsigned cand = (k == M) ? ~(unsigned)bi : 0u;   // max(~bi) = min bi
        unsigned L = wave_umax_dpp(cand);
        int widx = (int)~L;
        if (lane == r) { pkey = M; pix = widx; }
        if (k == M && bi == widx && bi != 0x7fffffff) {  // consuming lane
          cons |= 1u << ((unsigned)(bi - gtid) >> 13);   // STRIDE = 2^13
          bv = -3.3e38f; bi = 0x7fffffff;
#pragma unroll
          for (int kk = 0; kk < PPT; ++kk) {
            if (!((cons >> kk) & 1u)) {
              int i = gtid + kk * STRIDE;
              bool bt = (md[kk] > bv) || (md[kk] == bv && i < bi);
              bv = bt ? md[kk] : bv; bi = bt ? i : bi;
            }
          }
        }
      }

      // ---- publish: ONE packed 8B store/lane; lane0 release flag orders ----
      if (lane < TW) {
        ST_RLX(&slots[par * POOL + gw * TW + lane], pack_key32(pkey, pix));
      }
      if (lane == 0) ST_REL(flag + gw, batch);   // s_waitcnt vmcnt(0) + store

      // ---- poll all 128 wave-flags (minimal footprint: 2 words/lane) -----
      for (;;) {
        int f0 = LD_RLX(flag + lane);
        int f1 = LD_RLX(flag + 64 + lane);
        if (__ballot((f0 >= batch) && (f1 >= batch)) == ~0ull) break;
        __builtin_amdgcn_s_sleep(1);
      }
      __builtin_amdgcn_sched_barrier(0);   // no compiler motion across the poll

      // ---- readback pool ONCE: packed u64 x 16 entries/lane ----
      ull pk[RSLOTS];
#pragma unroll
      for (int j = 0; j < RSLOTS; ++j)
        pk[j] = LD_RLX(&slots[par * POOL + lane + 64 * j]);

      // ---- bucket keys; Mkey (global max bucket) and BmaxKey ----
      // entry e = lane + 64*j; e % 8 == lane % 8, so lanes with (lane&7)==7
      // hold exactly the 8th-published entries of all waves.
      unsigned kj[RSLOTS];
      unsigned lkmax = 0;
#pragma unroll
      for (int j = 0; j < RSLOTS; ++j) {
        kj[j] = (unsigned)(pk[j] >> 32);
        lkmax = (kj[j] > lkmax) ? kj[j] : lkmax;
      }
      const unsigned Mkey    = wave_umax_dpp(lkmax);
      const unsigned BmaxKey = wave_umax_dpp(((lane & 7) == 7) ? lkmax : 0u);

      int cap = N_ANCH - nsel;
      int S = 0;

      if (Mkey > BmaxKey) {
        // -------- typical path: compact live entries (key32 > BmaxKey) -----
        // each wave's own 8th entry <= BmaxKey -> <= 7 live/wave -> <= 896.
        // compacted key layout: key32<<32 | (0xFFFF-idx)<<16 | rank
        int base = 0;
#pragma unroll
        for (int j = 0; j < RSLOTS; ++j) {
          bool live = kj[j] > BmaxKey;
          ull bal = __ballot(live);
          int rank = base + (int)__popcll(bal & ((1ull << lane) - 1ull));
          if (live) {
            sm.f.lv[rank] = (pk[j] & 0xFFFFFFFF00000000ull)
                          | ((pk[j] & 0xFFFFull) << 16) | (ull)(unsigned)rank;
            int p = 0xFFFF - (int)(pk[j] & 0xFFFFull);
            sm.f.lc[rank][0] = pos[3 * p];
            sm.f.lc[rank][1] = pos[3 * p + 1];
            sm.f.lc[rank][2] = pos[3 * p + 2];
          }
          base += (int)__popcll(bal);
        }
        const int live_n = base;   // wave-uniform, 1..896

        // load compaction data to registers (guarded: only active 64-blocks)
        ull pk2[CCAP]; float c2x[CCAP], c2y[CCAP], c2z[CCAP];
#pragma unroll
        for (int tt = 0; tt < CCAP; ++tt) {
          if (live_n > tt * 64) {
            int e = tt * 64 + lane;
            bool ok = e < live_n;
            ull    v  = sm.f.lv[e];
            float  x  = sm.f.lc[e][0];
            float  y  = sm.f.lc[e][1];
            float  z  = sm.f.lc[e][2];
            pk2[tt] = ok ? v : 0ull;
            c2x[tt] = ok ? x : 0.0f;
            c2y[tt] = ok ? y : 0.0f;
            c2z[tt] = ok ? z : 0.0f;
          } else {
            pk2[tt] = 0ull;
            c2x[tt] = 0.0f; c2y[tt] = 0.0f; c2z[tt] = 0.0f;
          }
        }

        // ---- S-loop: zero-ballot zero-readlane chain; md inline (R4);
        // all CCAP loops guarded (wave-uniform) -- typical 2-5 active. ----
#pragma unroll 1
        while (S < cap) {
          // in-lane max over active packed keys
          ull wpk = pk2[0];
#pragma unroll
          for (int tt = 1; tt < CCAP; ++tt)
            if (live_n > tt * 64)
              wpk = (pk2[tt] > wpk) ? pk2[tt] : wpk;

          // phase 1: wave max of value key (hi32)
          unsigned hi = (unsigned)(wpk >> 32);
          unsigned M  = wave_umax_dpp(hi);
          if (S != 0 && !(M > BmaxKey)) break;
          // phase 2: among value-max holders, max lo32 = (idx-asc, rank)
          unsigned lo = (hi == M) ? (unsigned)wpk : 0u;
          unsigned L  = wave_umax_dpp(lo);
          ull full = ((ull)M << 32) | (ull)L;
          int widx = 0xFFFF - (int)((L >> 16) & 0xFFFFu);
          int rank = (int)(L & 0xFFFFu);
          float wx = sm.f.lc[rank][0];    // broadcast LDS read (no conflict)
          float wy = sm.f.lc[rank][1];
          float wz = sm.f.lc[rank][2];
          if (gw == 0 && lane == 0) ST_RLX(anchors + nsel + S, widx);

          // update packed keys: u64 min vs new-anchor distance key (low32
          // preserved: idx+rank). Winner dies (-> 0); dead slots stay 0.
#pragma unroll
          for (int tt = 0; tt < CCAP; ++tt) {
            if (live_n > tt * 64) {
              float d = dist32(c2x[tt], c2y[tt], c2z[tt], wx, wy, wz);
              ull dpk = ((ull)key32f(d) << 32) | (pk2[tt] & 0xFFFFFFFFull);
              ull nv  = (dpk < pk2[tt]) ? dpk : pk2[tt];
              pk2[tt] = (pk2[tt] == full) ? 0ull : nv;
            }
          }
          // inline apply to own md slice (bubble-filler under the chain)
#pragma unroll
          for (int k2 = 0; k2 < PPT; ++k2)
            md[k2] = fminf(md[k2], dist32(pdx[k2], pdy[k2], pdz[k2], wx, wy, wz));
          S++;
        }
      } else {
        // -------- fallback (bucket tie at Bmax; rare): packed-exact loop ----
#pragma unroll 1
        while (S < cap) {
          ull wpk = pk[0];
#pragma unroll
          for (int j = 1; j < RSLOTS; ++j) wpk = (pk[j] > wpk) ? pk[j] : wpk;
          ull g = wpk;
#pragma unroll
          for (int off = 1; off < 64; off <<= 1) {
            ull o = __shfl_xor(g, off);
            g = (o > g) ? o : g;
          }
          unsigned wkey = (unsigned)(g >> 32);
          if (S != 0 && !(wkey > BmaxKey)) break;
          int widx = 0xFFFF - (int)(g & 0xFFFFull);
          if (widx < 0) widx = 0;                      // sentinel clamp
          if (widx >= N_PTS) widx = N_PTS - 1;
          float wx = pos[3 * widx];
          float wy = pos[3 * widx + 1];
          float wz = pos[3 * widx + 2];
          if (gw == 0 && lane == 0) ST_RLX(anchors + nsel + S, widx);
#pragma unroll
          for (int j = 0; j < RSLOTS; ++j) {
            int p = 0xFFFF - (int)(pk[j] & 0xFFFFull);
            if (p < 0) p = 0;
            if (p >= N_PTS) p = N_PTS - 1;
            float d = dist32(pos[3 * p], pos[3 * p + 1], pos[3 * p + 2], wx, wy, wz);
            ull dpk = ((ull)key32f(d) << 32) | (pk[j] & 0xFFFFull);
            ull nv  = (dpk < pk[j]) ? dpk : pk[j];
            pk[j] = (pk[j] == g) ? 0ull : nv;
          }
#pragma unroll
          for (int k2 = 0; k2 < PPT; ++k2)
            md[k2] = fminf(md[k2], dist32(pdx[k2], pdy[k2], pdz[k2], wx, wy, wz));
          S++;
        }
      }
      nsel += S;

      // refresh thread-local argmax
      bv = -3.3e38f; bi = 0x7fffffff;
#pragma unroll
      for (int k = 0; k < PPT; ++k) {
        int i = gtid + k * STRIDE;
        bool bt = (md[k] > bv) || (md[k] == bv && i < bi);
        bv = bt ? md[k] : bv; bi = bt ? i : bi;
      }
    }
  } else {
    // =============== KNN: one wave per anchor (no barriers) ===============
    const int aidx = blockIdx.x - NFB;
    int a = -1;
    for (;;) {
      if (lane == 0) a = LD_RLX(anchors + aidx);
      a = __shfl(a, 0);
      if (a >= 0) break;
      __builtin_amdgcn_s_sleep(32);
    }
    const int ai = a;
    const float ax = pos[3 * ai], ay = pos[3 * ai + 1], az = pos[3 * ai + 2];

    // per-lane top-20 (u64 keys, static indexing ONLY -> stays in VGPRs)
    ull key[KNN];
#pragma unroll
    for (int s = 0; s < KNN; ++s) key[s] = ~0ull;
    ull kmax = ~0ull; int smax = 0;
#pragma unroll 1
    for (int k = 0; k < N_PTS / 64; ++k) {   // 625 candidates per lane, exact
      int j = (k << 6) + lane;
      float dx = pos[3 * j] - ax, dy = pos[3 * j + 1] - ay, dz = pos[3 * j + 2] - az;
      float d  = dx * dx + dy * dy + dz * dz;
      ull nk = ((ull)__float_as_uint(d) << 32) | (unsigned)j;
      if (nk < kmax) {
#pragma unroll
        for (int s = 0; s < KNN; ++s) key[s] = (s == smax) ? nk : key[s];
        kmax = 0ull; smax = 0;
#pragma unroll
        for (int s = 0; s < KNN; ++s) {
          bool g = key[s] > kmax;
          kmax = g ? key[s] : kmax;
          smax = g ? s : smax;
        }
      }
    }

    // wave-wide merge: 20 extract-min rounds (shuffle butterfly, no LDS sync)
    ull lmin = ~0ull; int ls = 0;
#pragma unroll
    for (int s = 0; s < KNN; ++s) {
      bool l = key[s] < lmin;
      lmin = l ? key[s] : lmin; ls = l ? s : ls;
    }
#pragma unroll 1
    for (int r = 0; r < KNN; ++r) {
      ull g = lmin;
#pragma unroll
      for (int off = 1; off < 64; off <<= 1) {
        ull ov = __shfl_xor(g, off);
        g = (ov < g) ? ov : g;
      }
      if (lane == 0) sm.k.w[r] = (int)(g & 0xffffffffull);
      if (lmin == g) {          // unique owner consumes & rescans (all static)
#pragma unroll
        for (int s = 0; s < KNN; ++s) key[s] = (s == ls) ? ~0ull : key[s];
        lmin = ~0ull; ls = 0;
#pragma unroll
        for (int s = 0; s < KNN; ++s) {
          bool l = key[s] < lmin;
          lmin = l ? key[s] : lmin; ls = l ? s : ls;
        }
      }
    }

    if (lane == 0) {
      double mx = 0, my = 0, mz = 0;
      for (int r = 0; r < KNN; ++r) {
        int p = sm.k.w[r];
        mx += (double)pos[3 * p]; my += (double)pos[3 * p + 1]; mz += (double)pos[3 * p + 2];
      }
      mx /= KNN; my /= KNN; mz /= KNN;
      double xx = 0, xy = 0, xz = 0, yy = 0, yz = 0, zz = 0;
      for (int r = 0; r < KNN; ++r) {
        int p = sm.k.w[r];
        double cx = (double)pos[3 * p]     - mx;
        double cy = (double)pos[3 * p + 1] - my;
        double cz = (double)pos[3 * p + 2] - mz;
        xx += cx * cx; xy += cx * cy; xz += cx * cz;
        yy += cy * cy; yz += cy * cz; zz += cz * cz;
      }
      double v0, v1, v2;
      eig3_maxvec(xx, xy, xz, yy, yz, zz, v0, v1, v2);

      double a0 = vec_pred[3 * aidx], a1 = vec_pred[3 * aidx + 1], a2 = vec_pred[3 * aidx + 2];
      double an = sqrt(a0 * a0 + a1 * a1 + a2 * a2);
      double bn = sqrt(v0 * v0 + v1 * v1 + v2 * v2);
      double denom = fmax(an, 1e-8) * fmax(bn, 1e-8);
      double c = fabs((a0 * v0 + a1 * v1 + a2 * v2) / denom);
      atomicAdd(acc, log(c + 1e-6));
    }
  }
}

__global__ void finalize_kernel(const double* __restrict__ acc, float* __restrict__ out) {
  out[0] = (float)(-acc[0] / (double)N_ANCH);
}

// ===========================================================================
extern "C" void kernel_launch(void* const* d_in, const int* in_sizes, int n_in,
                              void* d_out, int out_size, void* d_ws, size_t ws_size,
                              hipStream_t stream) {
  (void)in_sizes; (void)n_in; (void)out_size; (void)ws_size;
  const float* vec_pred = (const float*)d_in[0];
  const float* pos      = (const float*)d_in[1];
  float* out = (float*)d_out;

  char* ws = (char*)d_ws;
  double* acc     = (double*)(ws + 0);
  int*    flag    = (int*)(ws + 64);
  ull*    slots   = (ull*)(ws + 1024);
  int*    anchors = (int*)(ws + 17408);

  hipMemsetAsync(ws, 0, 1024, stream);                   // acc + flags
  hipMemsetAsync(ws + 17408, 0xFF, N_ANCH * 4, stream);  // anchors = -1
  hipLaunchKernelGGL(fps_knn_kernel, dim3(NFB + N_ANCH), dim3(BT), 0, stream,
                     pos, vec_pred, flag, slots, anchors, acc);
  hipLaunchKernelGGL(finalize_kernel, dim3(1), dim3(1), 0, stream, acc, out);
}

// Round 12
// 3313.378 us; speedup vs baseline: 1.1754x; 1.1754x over previous
//
#include <hip/hip_runtime.h>
#include <math.h>

#define N_PTS       40000
#define N_ANCH      4000     // ceil(0.1 * 40000)
#define KNN         20
#define NFB         128      // fps blocks (1 wave each)
#define BT          64       // threads per block (all blocks) = 1 wave
#define NWAVES      128                // fps waves
#define STRIDE      (NWAVES * 64)      // 8192 = 2^13
#define PPT         5                  // 8192*5 = 40960 >= 40000
#define TW          4                  // published candidates per WAVE (optimal: R8/R11 prove TW=8 loses)
#define POOL        (NWAVES * TW)      // 512
#define RSLOTS      (POOL / 64)        // 8 readback entries per lane
#define CCAP        6                  // compacted capacity/lane (384 hard bound)

typedef unsigned long long ull;

#define LD_RLX(p)    __hip_atomic_load((p),  __ATOMIC_RELAXED, __HIP_MEMORY_SCOPE_AGENT)
#define ST_REL(p,v)  __hip_atomic_store((p), (v), __ATOMIC_RELEASE, __HIP_MEMORY_SCOPE_AGENT)
#define ST_RLX(p,v)  __hip_atomic_store((p), (v), __ATOMIC_RELAXED, __HIP_MEMORY_SCOPE_AGENT)

// Workspace layout (identical to R10):
//   off     0 : double acc               (zeroed)
//   off    64 : int flag[128]            (zeroed; per-wave monotone batch counters)
//   off  1024 : ull slots[2][512]        (parity x pool, packed {key32|idx16}; 8 KB)
//   off 17408 : int anchors[4000]        (memset 0xFF -> -1)
//
// R11 post-mortem: C (~9-11us/batch) dominates and only ~3-4us is accountable
// serial latency; the rest is coherent-point queueing. Biggest background
// load: 4000 KNN spinner waves polling anchors[] agent-scope every ~3000cyc
// (~1.3 lines/cyc -- more than the FPS poll itself). This round: (1) KNN
// arrival-scheduled pre-sleep + slow poll, (2) publish slots spread through
// the extraction rounds so the release-drain is free, (3) paired 8B flag
// poll at half the instruction count.

__device__ __forceinline__ float dist32(float px, float py, float pz,
                                        float wx, float wy, float wz) {
  float dx = px - wx, dy = py - wy, dz = pz - wz;
  return dx * dx + dy * dy + dz * dz;
}

// monotone u32 key from f32 (exact order embedding)
__device__ __forceinline__ unsigned key32f(float v) {
  unsigned b = __float_as_uint(v);
  return (b & 0x80000000u) ? ~b : (b | 0x80000000u);
}

// published slot: (value-desc, idx-asc) as ONE u64.
__device__ __forceinline__ ull pack_key32(unsigned key, int idx) {
  return ((ull)key << 32) | (ull)((0xFFFF - idx) & 0xFFFF);
}

// wave-wide max of u32 via DPP (VALU only); returns wave-uniform max
__device__ __forceinline__ unsigned wave_umax_dpp(unsigned x) {
#define DPP_STEP(ctrl) { unsigned y = (unsigned)__builtin_amdgcn_update_dpp( \
      0, (int)x, ctrl, 0xf, 0xf, true); x = (y > x) ? y : x; }
  DPP_STEP(0x111)  // row_shr:1
  DPP_STEP(0x112)  // row_shr:2
  DPP_STEP(0x114)  // row_shr:4
  DPP_STEP(0x118)  // row_shr:8
  DPP_STEP(0x142)  // row_bcast:15
  DPP_STEP(0x143)  // row_bcast:31
#undef DPP_STEP
  return (unsigned)__builtin_amdgcn_readlane((int)x, 63);
}

struct FpsSm {                 // single-wave compaction buffers (7680 B)
  ull    lv[CCAP * 64];        // packed keys (with rank in low 16)
  float  lc[CCAP * 64][3];     // coords indexed by rank
};
struct KnnSm { int w[KNN]; };
union Smem { FpsSm f; KnnSm k; };

// ============== symmetric 3x3: eigenvector of largest eigenvalue ===========
__device__ static inline void eig3_maxvec(double xx, double xy, double xz,
                                          double yy, double yz, double zz,
                                          double& v0, double& v1, double& v2) {
  double q  = (xx + yy + zz) / 3.0;
  double p1 = xy * xy + xz * xz + yz * yz;
  double a00 = xx - q, a11 = yy - q, a22 = zz - q;
  double p2 = a00 * a00 + a11 * a11 + a22 * a22 + 2.0 * p1;
  if (p2 < 1e-300) { v0 = 1.0; v1 = 0.0; v2 = 0.0; return; }
  double p   = sqrt(p2 / 6.0);
  double inv = 1.0 / p;
  double b00 = a00 * inv, b01 = xy * inv, b02 = xz * inv;
  double b11 = a11 * inv, b12 = yz * inv, b22 = a22 * inv;
  double detB = b00 * (b11 * b22 - b12 * b12)
              - b01 * (b01 * b22 - b12 * b02)
              + b02 * (b01 * b12 - b11 * b02);
  double r = fmin(1.0, fmax(-1.0, detB * 0.5));
  double phi = acos(r) / 3.0;
  double lam = q + 2.0 * p * cos(phi);   // largest eigenvalue

  double r0x = xx - lam, r0y = xy,       r0z = xz;
  double r1x = xy,       r1y = yy - lam, r1z = yz;
  double r2x = xz,       r2y = yz,       r2z = zz - lam;
  double c0x = r0y * r1z - r0z * r1y, c0y = r0z * r1x - r0x * r1z, c0z = r0x * r1y - r0y * r1x;
  double c1x = r0y * r2z - r0z * r2y, c1y = r0z * r2x - r0x * r2z, c1z = r0x * r2y - r0y * r2x;
  double c2x = r1y * r2z - r1z * r2y, c2y = r1z * r2x - r1x * r2z, c2z = r1x * r2y - r1y * r2x;
  double n0 = c0x * c0x + c0y * c0y + c0z * c0z;
  double n1 = c1x * c1x + c1y * c1y + c1z * c1z;
  double n2 = c2x * c2x + c2y * c2y + c2z * c2z;
  double bx = c0x, by = c0y, bz = c0z, bn = n0;
  if (n1 > bn) { bx = c1x; by = c1y; bz = c1z; bn = n1; }
  if (n2 > bn) { bx = c2x; by = c2y; bz = c2z; bn = n2; }
  if (bn < 1e-280) { v0 = 1.0; v1 = 0.0; v2 = 0.0; return; }
  double s = 1.0 / sqrt(bn);
  v0 = bx * s; v1 = by * s; v2 = bz * s;
}

// ===========================================================================
__global__ __launch_bounds__(BT, 2) void fps_knn_kernel(
    const float* __restrict__ pos, const float* __restrict__ vec_pred,
    int* __restrict__ flag, ull* __restrict__ slots,
    int* __restrict__ anchors, double* __restrict__ acc) {
  __shared__ Smem sm;
  const int lane = threadIdx.x & 63;

  if (blockIdx.x < NFB) {
    // ============ FPS: one wave per block, wave-autonomous ================
    __builtin_amdgcn_s_setprio(1);   // FPS is the critical path (R0: +2-3%)

    const int gw   = blockIdx.x;       // global wave id, 0..127
    const int gtid = gw * 64 + lane;

    float pdx[PPT], pdy[PPT], pdz[PPT], md[PPT];   // f32 coords + min-dist
    const float a0x = pos[0], a0y = pos[1], a0z = pos[2];
#pragma unroll
    for (int k = 0; k < PPT; ++k) {
      int i = gtid + k * STRIDE;
      if (i < N_PTS) {
        pdx[k] = pos[3 * i];
        pdy[k] = pos[3 * i + 1];
        pdz[k] = pos[3 * i + 2];
        md[k]  = dist32(pdx[k], pdy[k], pdz[k], a0x, a0y, a0z);
      } else {
        pdx[k] = 0.0f; pdy[k] = 0.0f; pdz[k] = 0.0f;
        md[k]  = -3.0e38f;   // pad: never beats real md >= 0
      }
    }
    if (gw == 0 && lane == 0) ST_RLX(anchors + 0, 0);

    float bv = -3.3e38f; int bi = 0x7fffffff;
#pragma unroll
    for (int k = 0; k < PPT; ++k) {
      int i = gtid + k * STRIDE;
      bool bt = (md[k] > bv) || (md[k] == bv && i < bi);
      bv = bt ? md[k] : bv; bi = bt ? i : bi;
    }

    int nsel  = 1;
    int batch = 0;
#pragma unroll 1
    while (nsel < N_ANCH) {
      batch++;
      const int par = batch & 1;

      // ---- per-wave top-4 extraction: two-phase DPP; slot r is stored
      //      inside round r so the 4 agent-scope stores drain DURING the
      //      extraction -> the release-flag's vmcnt(0) is nearly free. ----
      unsigned cons = 0;
#pragma unroll 1
      for (int r = 0; r < TW; ++r) {
        unsigned k = key32f(bv);
        unsigned M = wave_umax_dpp(k);
        unsigned cand = (k == M) ? ~(unsigned)bi : 0u;   // max(~bi) = min bi
        unsigned L = wave_umax_dpp(cand);
        int widx = (int)~L;
        if (lane == r)
          ST_RLX(&slots[par * POOL + gw * TW + r], pack_key32(M, widx));
        if (k == M && bi == widx && bi != 0x7fffffff) {  // consuming lane
          cons |= 1u << ((unsigned)(bi - gtid) >> 13);   // STRIDE = 2^13
          bv = -3.3e38f; bi = 0x7fffffff;
#pragma unroll
          for (int kk = 0; kk < PPT; ++kk) {
            if (!((cons >> kk) & 1u)) {
              int i = gtid + kk * STRIDE;
              bool bt = (md[kk] > bv) || (md[kk] == bv && i < bi);
              bv = bt ? md[kk] : bv; bi = bt ? i : bi;
            }
          }
        }
      }
      if (lane == 0) ST_REL(flag + gw, batch);   // drain (cheap now) + store

      // ---- poll all 128 wave-flags: ONE paired 8B load per lane ----------
      {
        const ull* flag2 = (const ull*)flag;
        for (;;) {
          ull f = LD_RLX(flag2 + lane);
          int f0 = (int)(unsigned)(f & 0xffffffffull);
          int f1 = (int)(unsigned)(f >> 32);
          if (__ballot((f0 >= batch) && (f1 >= batch)) == ~0ull) break;
          __builtin_amdgcn_s_sleep(2);
        }
      }
      __builtin_amdgcn_sched_barrier(0);   // no compiler motion across the poll

      // ---- readback pool ONCE: packed u64 x 8 entries/lane ----
      ull pk[RSLOTS];
#pragma unroll
      for (int j = 0; j < RSLOTS; ++j)
        pk[j] = LD_RLX(&slots[par * POOL + lane + 64 * j]);

      // ---- bucket keys; Mkey (global max bucket) and BmaxKey ----
      unsigned kj[RSLOTS];
      unsigned lkmax = 0;
#pragma unroll
      for (int j = 0; j < RSLOTS; ++j) {
        kj[j] = (unsigned)(pk[j] >> 32);
        lkmax = (kj[j] > lkmax) ? kj[j] : lkmax;
      }
      const unsigned Mkey    = wave_umax_dpp(lkmax);
      const unsigned BmaxKey = wave_umax_dpp(((lane & 3) == 3) ? lkmax : 0u);

      int cap = N_ANCH - nsel;
      int S = 0;

      if (Mkey > BmaxKey) {
        // -------- typical path: compact live entries (key32 > BmaxKey) -----
        // compacted key layout: key32<<32 | (0xFFFF-idx)<<16 | rank
        int base = 0;
#pragma unroll
        for (int j = 0; j < RSLOTS; ++j) {
          bool live = kj[j] > BmaxKey;
          ull bal = __ballot(live);
          int rank = base + (int)__popcll(bal & ((1ull << lane) - 1ull));
          if (live) {
            sm.f.lv[rank] = (pk[j] & 0xFFFFFFFF00000000ull)
                          | ((pk[j] & 0xFFFFull) << 16) | (ull)(unsigned)rank;
            int p = 0xFFFF - (int)(pk[j] & 0xFFFFull);
            sm.f.lc[rank][0] = pos[3 * p];
            sm.f.lc[rank][1] = pos[3 * p + 1];
            sm.f.lc[rank][2] = pos[3 * p + 2];
          }
          base += (int)__popcll(bal);
        }
        const int live_n = base;   // wave-uniform, 1..384

        // load compaction data to registers (packed key + f32 coords)
        ull pk2[CCAP]; float c2x[CCAP], c2y[CCAP], c2z[CCAP];
#pragma unroll
        for (int tt = 0; tt < CCAP; ++tt) {
          if (live_n > tt * 64) {
            int e = tt * 64 + lane;
            bool ok = e < live_n;
            ull    v  = sm.f.lv[e];
            float  x  = sm.f.lc[e][0];
            float  y  = sm.f.lc[e][1];
            float  z  = sm.f.lc[e][2];
            pk2[tt] = ok ? v : 0ull;
            c2x[tt] = ok ? x : 0.0f;
            c2y[tt] = ok ? y : 0.0f;
            c2z[tt] = ok ? z : 0.0f;
          } else {
            pk2[tt] = 0ull;
            c2x[tt] = 0.0f; c2y[tt] = 0.0f; c2z[tt] = 0.0f;
          }
        }

        // ---- S-loop: zero-ballot zero-readlane chain; md inline (R4) ----
#pragma unroll 1
        while (S < cap) {
          // in-lane max over 6 packed keys
          ull wpk = pk2[0];
#pragma unroll
          for (int tt = 1; tt < CCAP; ++tt)
            wpk = (pk2[tt] > wpk) ? pk2[tt] : wpk;

          // phase 1: wave max of value key (hi32)
          unsigned hi = (unsigned)(wpk >> 32);
          unsigned M  = wave_umax_dpp(hi);
          if (S != 0 && !(M > BmaxKey)) break;
          // phase 2: among value-max holders, max lo32 = (idx-asc, rank)
          unsigned lo = (hi == M) ? (unsigned)wpk : 0u;
          unsigned L  = wave_umax_dpp(lo);
          ull full = ((ull)M << 32) | (ull)L;
          int widx = 0xFFFF - (int)((L >> 16) & 0xFFFFu);
          int rank = (int)(L & 0xFFFFu);
          float wx = sm.f.lc[rank][0];    // broadcast LDS read (no conflict)
          float wy = sm.f.lc[rank][1];
          float wz = sm.f.lc[rank][2];
          if (gw == 0 && lane == 0) ST_RLX(anchors + nsel + S, widx);

          // update packed keys: u64 min vs new-anchor distance key (low32
          // preserved: idx+rank). Winner dies (-> 0); dead slots stay 0.
#pragma unroll
          for (int tt = 0; tt < CCAP; ++tt) {
            if (live_n > tt * 64) {
              float d = dist32(c2x[tt], c2y[tt], c2z[tt], wx, wy, wz);
              ull dpk = ((ull)key32f(d) << 32) | (pk2[tt] & 0xFFFFFFFFull);
              ull nv  = (dpk < pk2[tt]) ? dpk : pk2[tt];
              pk2[tt] = (pk2[tt] == full) ? 0ull : nv;
            }
          }
          // inline apply to own md slice (bubble-filler under the chain)
#pragma unroll
          for (int k2 = 0; k2 < PPT; ++k2)
            md[k2] = fminf(md[k2], dist32(pdx[k2], pdy[k2], pdz[k2], wx, wy, wz));
          S++;
        }
      } else {
        // -------- fallback (bucket tie at Bmax; rare): packed-exact loop ----
#pragma unroll 1
        while (S < cap) {
          ull wpk = pk[0];
#pragma unroll
          for (int j = 1; j < RSLOTS; ++j) wpk = (pk[j] > wpk) ? pk[j] : wpk;
          ull g = wpk;
#pragma unroll
          for (int off = 1; off < 64; off <<= 1) {
            ull o = __shfl_xor(g, off);
            g = (o > g) ? o : g;
          }
          unsigned wkey = (unsigned)(g >> 32);
          if (S != 0 && !(wkey > BmaxKey)) break;
          int widx = 0xFFFF - (int)(g & 0xFFFFull);
          if (widx < 0) widx = 0;                      // sentinel clamp
          if (widx >= N_PTS) widx = N_PTS - 1;
          float wx = pos[3 * widx];
          float wy = pos[3 * widx + 1];
          float wz = pos[3 * widx + 2];
          if (gw == 0 && lane == 0) ST_RLX(anchors + nsel + S, widx);
#pragma unroll
          for (int j = 0; j < RSLOTS; ++j) {
            int p = 0xFFFF - (int)(pk[j] & 0xFFFFull);
            if (p < 0) p = 0;
            if (p >= N_PTS) p = N_PTS - 1;
            float d = dist32(pos[3 * p], pos[3 * p + 1], pos[3 * p + 2], wx, wy, wz);
            ull dpk = ((ull)key32f(d) << 32) | (pk[j] & 0xFFFFull);
            ull nv  = (dpk < pk[j]) ? dpk : pk[j];
            pk[j] = (pk[j] == g) ? 0ull : nv;
          }
#pragma unroll
          for (int k2 = 0; k2 < PPT; ++k2)
            md[k2] = fminf(md[k2], dist32(pdx[k2], pdy[k2], pdz[k2], wx, wy, wz));
          S++;
        }
      }
      nsel += S;

      // refresh thread-local argmax
      bv = -3.3e38f; bi = 0x7fffffff;
#pragma unroll
      for (int k = 0; k < PPT; ++k) {
        int i = gtid + k * STRIDE;
        bool bt = (md[k] > bv) || (md[k] == bv && i < bi);
        bv = bt ? md[k] : bv; bi = bt ? i : bi;
      }
    }
  } else {
    // =============== KNN: one wave per anchor (no barriers) ===============
    // Arrival-scheduled wait: anchor aidx arrives ~0.67*aidx us into FPS;
    // pre-sleep ~0.43*aidx us (35% safety margin) then slow-poll at ~3.4us.
    // Cuts background agent-scope poll traffic (4000 waves) ~5-10x -- that
    // traffic queues at the same coherence point as the FPS sync (R11 fit).
    const int aidx = blockIdx.x - NFB;
    const int pre = aidx >> 3;           // pre-sleep chunks of ~3.4us
#pragma unroll 1
    for (int w = 0; w < pre; ++w) __builtin_amdgcn_s_sleep(127);
    int a = -1;
    for (;;) {
      if (lane == 0) a = LD_RLX(anchors + aidx);
      a = __shfl(a, 0);
      if (a >= 0) break;
      __builtin_amdgcn_s_sleep(127);
    }
    const int ai = a;
    const float ax = pos[3 * ai], ay = pos[3 * ai + 1], az = pos[3 * ai + 2];

    // per-lane top-20 (u64 keys, static indexing ONLY -> stays in VGPRs)
    ull key[KNN];
#pragma unroll
    for (int s = 0; s < KNN; ++s) key[s] = ~0ull;
    ull kmax = ~0ull; int smax = 0;
#pragma unroll 1
    for (int k = 0; k < N_PTS / 64; ++k) {   // 625 candidates per lane, exact
      int j = (k << 6) + lane;
      float dx = pos[3 * j] - ax, dy = pos[3 * j + 1] - ay, dz = pos[3 * j + 2] - az;
      float d  = dx * dx + dy * dy + dz * dz;
      ull nk = ((ull)__float_as_uint(d) << 32) | (unsigned)j;
      if (nk < kmax) {
#pragma unroll
        for (int s = 0; s < KNN; ++s) key[s] = (s == smax) ? nk : key[s];
        kmax = 0ull; smax = 0;
#pragma unroll
        for (int s = 0; s < KNN; ++s) {
          bool g = key[s] > kmax;
          kmax = g ? key[s] : kmax;
          smax = g ? s : smax;
        }
      }
    }

    // wave-wide merge: 20 extract-min rounds (shuffle butterfly, no LDS sync)
    ull lmin = ~0ull; int ls = 0;
#pragma unroll
    for (int s = 0; s < KNN; ++s) {
      bool l = key[s] < lmin;
      lmin = l ? key[s] : lmin; ls = l ? s : ls;
    }
#pragma unroll 1
    for (int r = 0; r < KNN; ++r) {
      ull g = lmin;
#pragma unroll
      for (int off = 1; off < 64; off <<= 1) {
        ull ov = __shfl_xor(g, off);
        g = (ov < g) ? ov : g;
      }
      if (lane == 0) sm.k.w[r] = (int)(g & 0xffffffffull);
      if (lmin == g) {          // unique owner consumes & rescans (all static)
#pragma unroll
        for (int s = 0; s < KNN; ++s) key[s] = (s == ls) ? ~0ull : key[s];
        lmin = ~0ull; ls = 0;
#pragma unroll
        for (int s = 0; s < KNN; ++s) {
          bool l = key[s] < lmin;
          lmin = l ? key[s] : lmin; ls = l ? s : ls;
        }
      }
    }

    if (lane == 0) {
      double mx = 0, my = 0, mz = 0;
      for (int r = 0; r < KNN; ++r) {
        int p = sm.k.w[r];
        mx += (double)pos[3 * p]; my += (double)pos[3 * p + 1]; mz += (double)pos[3 * p + 2];
      }
      mx /= KNN; my /= KNN; mz /= KNN;
      double xx = 0, xy = 0, xz = 0, yy = 0, yz = 0, zz = 0;
      for (int r = 0; r < KNN; ++r) {
        int p = sm.k.w[r];
        double cx = (double)pos[3 * p]     - mx;
        double cy = (double)pos[3 * p + 1] - my;
        double cz = (double)pos[3 * p + 2] - mz;
        xx += cx * cx; xy += cx * cy; xz += cx * cz;
        yy += cy * cy; yz += cy * cz; zz += cz * cz;
      }
      double v0, v1, v2;
      eig3_maxvec(xx, xy, xz, yy, yz, zz, v0, v1, v2);

      double a0 = vec_pred[3 * aidx], a1 = vec_pred[3 * aidx + 1], a2 = vec_pred[3 * aidx + 2];
      double an = sqrt(a0 * a0 + a1 * a1 + a2 * a2);
      double bn = sqrt(v0 * v0 + v1 * v1 + v2 * v2);
      double denom = fmax(an, 1e-8) * fmax(bn, 1e-8);
      double c = fabs((a0 * v0 + a1 * v1 + a2 * v2) / denom);
      atomicAdd(acc, log(c + 1e-6));
    }
  }
}

__global__ void finalize_kernel(const double* __restrict__ acc, float* __restrict__ out) {
  out[0] = (float)(-acc[0] / (double)N_ANCH);
}

// ===========================================================================
extern "C" void kernel_launch(void* const* d_in, const int* in_sizes, int n_in,
                              void* d_out, int out_size, void* d_ws, size_t ws_size,
                              hipStream_t stream) {
  (void)in_sizes; (void)n_in; (void)out_size; (void)ws_size;
  const float* vec_pred = (const float*)d_in[0];
  const float* pos      = (const float*)d_in[1];
  float* out = (float*)d_out;

  char* ws = (char*)d_ws;
  double* acc     = (double*)(ws + 0);
  int*    flag    = (int*)(ws + 64);
  ull*    slots   = (ull*)(ws + 1024);
  int*    anchors = (int*)(ws + 17408);

  hipMemsetAsync(ws, 0, 1024, stream);                   // acc + flags
  hipMemsetAsync(ws + 17408, 0xFF, N_ANCH * 4, stream);  // anchors = -1
  hipLaunchKernelGGL(fps_knn_kernel, dim3(NFB + N_ANCH), dim3(BT), 0, stream,
                     pos, vec_pred, flag, slots, anchors, acc);
  hipLaunchKernelGGL(finalize_kernel, dim3(1), dim3(1), 0, stream, acc, out);
}

// Round 13
// 3305.890 us; speedup vs baseline: 1.1781x; 1.0023x over previous
//
#include <hip/hip_runtime.h>
#include <math.h>

#define N_PTS       40000
#define N_ANCH      4000     // ceil(0.1 * 40000)
#define KNN         20
#define NFB         64       // fps blocks (1 wave each) -- halved vs R10
#define BT          64       // threads per block (all blocks) = 1 wave
#define NWAVES      64                 // fps waves
#define STRIDE      (NWAVES * 64)      // 4096 = 2^12
#define PPT         10                 // 4096*10 = 40960 >= 40000
#define TW          8                  // published candidates per WAVE (B=126, R2-measured)
#define POOL        (NWAVES * TW)      // 512
#define RSLOTS      (POOL / 64)        // 8 readback entries per lane
#define CCAP        7                  // compacted capacity/lane (448 = 7/wave x 64, tight)

typedef unsigned long long ull;

#define LD_RLX(p)    __hip_atomic_load((p),  __ATOMIC_RELAXED, __HIP_MEMORY_SCOPE_AGENT)
#define ST_REL(p,v)  __hip_atomic_store((p), (v), __ATOMIC_RELEASE, __HIP_MEMORY_SCOPE_AGENT)
#define ST_RLX(p,v)  __hip_atomic_store((p), (v), __ATOMIC_RELAXED, __HIP_MEMORY_SCOPE_AGENT)

// Workspace layout:
//   off     0 : double acc               (zeroed)
//   off    64 : int flag[64]             (zeroed; per-wave monotone batch counters)
//   off  1024 : ull slots[2][512]        (parity x pool, packed {key32|idx16}; 8 KB)
//   off 17408 : int anchors[4000]        (memset 0xFF -> -1)
//
// R12 lesson: agent-scope stores must be batched into ONE wave-level
// instruction (coalesced 32B+ transactions); spreading them doubled
// WRITE_SIZE and cost 3us/batch. R11/R12 model: C scales with writer/
// poller count -> this round halves the wave count (64 x TW=8, the
// R2-measured B=126 geometry) now that alpha is f32+zero-crosslane cheap.

__device__ __forceinline__ float dist32(float px, float py, float pz,
                                        float wx, float wy, float wz) {
  float dx = px - wx, dy = py - wy, dz = pz - wz;
  return dx * dx + dy * dy + dz * dz;
}

// monotone u32 key from f32 (exact order embedding)
__device__ __forceinline__ unsigned key32f(float v) {
  unsigned b = __float_as_uint(v);
  return (b & 0x80000000u) ? ~b : (b | 0x80000000u);
}

// published slot: (value-desc, idx-asc) as ONE u64.
__device__ __forceinline__ ull pack_key32(unsigned key, int idx) {
  return ((ull)key << 32) | (ull)((0xFFFF - idx) & 0xFFFF);
}

// wave-wide max of u32 via DPP (VALU only); returns wave-uniform max
__device__ __forceinline__ unsigned wave_umax_dpp(unsigned x) {
#define DPP_STEP(ctrl) { unsigned y = (unsigned)__builtin_amdgcn_update_dpp( \
      0, (int)x, ctrl, 0xf, 0xf, true); x = (y > x) ? y : x; }
  DPP_STEP(0x111)  // row_shr:1
  DPP_STEP(0x112)  // row_shr:2
  DPP_STEP(0x114)  // row_shr:4
  DPP_STEP(0x118)  // row_shr:8
  DPP_STEP(0x142)  // row_bcast:15
  DPP_STEP(0x143)  // row_bcast:31
#undef DPP_STEP
  return (unsigned)__builtin_amdgcn_readlane((int)x, 63);
}

struct FpsSm {                 // single-wave compaction buffers (8960 B)
  ull    lv[CCAP * 64];        // packed keys (with rank in low 16)
  float  lc[CCAP * 64][3];     // coords indexed by rank
};
struct KnnSm { int w[KNN]; };
union Smem { FpsSm f; KnnSm k; };

// ============== symmetric 3x3: eigenvector of largest eigenvalue ===========
__device__ static inline void eig3_maxvec(double xx, double xy, double xz,
                                          double yy, double yz, double zz,
                                          double& v0, double& v1, double& v2) {
  double q  = (xx + yy + zz) / 3.0;
  double p1 = xy * xy + xz * xz + yz * yz;
  double a00 = xx - q, a11 = yy - q, a22 = zz - q;
  double p2 = a00 * a00 + a11 * a11 + a22 * a22 + 2.0 * p1;
  if (p2 < 1e-300) { v0 = 1.0; v1 = 0.0; v2 = 0.0; return; }
  double p   = sqrt(p2 / 6.0);
  double inv = 1.0 / p;
  double b00 = a00 * inv, b01 = xy * inv, b02 = xz * inv;
  double b11 = a11 * inv, b12 = yz * inv, b22 = a22 * inv;
  double detB = b00 * (b11 * b22 - b12 * b12)
              - b01 * (b01 * b22 - b12 * b02)
              + b02 * (b01 * b12 - b11 * b02);
  double r = fmin(1.0, fmax(-1.0, detB * 0.5));
  double phi = acos(r) / 3.0;
  double lam = q + 2.0 * p * cos(phi);   // largest eigenvalue

  double r0x = xx - lam, r0y = xy,       r0z = xz;
  double r1x = xy,       r1y = yy - lam, r1z = yz;
  double r2x = xz,       r2y = yz,       r2z = zz - lam;
  double c0x = r0y * r1z - r0z * r1y, c0y = r0z * r1x - r0x * r1z, c0z = r0x * r1y - r0y * r1x;
  double c1x = r0y * r2z - r0z * r2y, c1y = r0z * r2x - r0x * r2z, c1z = r0x * r2y - r0y * r2x;
  double c2x = r1y * r2z - r1z * r2y, c2y = r1z * r2x - r1x * r2z, c2z = r1x * r2y - r1y * r2x;
  double n0 = c0x * c0x + c0y * c0y + c0z * c0z;
  double n1 = c1x * c1x + c1y * c1y + c1z * c1z;
  double n2 = c2x * c2x + c2y * c2y + c2z * c2z;
  double bx = c0x, by = c0y, bz = c0z, bn = n0;
  if (n1 > bn) { bx = c1x; by = c1y; bz = c1z; bn = n1; }
  if (n2 > bn) { bx = c2x; by = c2y; bz = c2z; bn = n2; }
  if (bn < 1e-280) { v0 = 1.0; v1 = 0.0; v2 = 0.0; return; }
  double s = 1.0 / sqrt(bn);
  v0 = bx * s; v1 = by * s; v2 = bz * s;
}

// ===========================================================================
__global__ __launch_bounds__(BT, 2) void fps_knn_kernel(
    const float* __restrict__ pos, const float* __restrict__ vec_pred,
    int* __restrict__ flag, ull* __restrict__ slots,
    int* __restrict__ anchors, double* __restrict__ acc) {
  __shared__ Smem sm;
  const int lane = threadIdx.x & 63;

  if (blockIdx.x < NFB) {
    // ============ FPS: one wave per block, wave-autonomous ================
    __builtin_amdgcn_s_setprio(1);   // FPS is the critical path (R0: +2-3%)

    const int gw   = blockIdx.x;       // global wave id, 0..63
    const int gtid = gw * 64 + lane;

    float pdx[PPT], pdy[PPT], pdz[PPT], md[PPT];   // f32 coords + min-dist
    const float a0x = pos[0], a0y = pos[1], a0z = pos[2];
#pragma unroll
    for (int k = 0; k < PPT; ++k) {
      int i = gtid + k * STRIDE;
      if (i < N_PTS) {
        pdx[k] = pos[3 * i];
        pdy[k] = pos[3 * i + 1];
        pdz[k] = pos[3 * i + 2];
        md[k]  = dist32(pdx[k], pdy[k], pdz[k], a0x, a0y, a0z);
      } else {
        pdx[k] = 0.0f; pdy[k] = 0.0f; pdz[k] = 0.0f;
        md[k]  = -3.0e38f;   // pad: never beats real md >= 0
      }
    }
    if (gw == 0 && lane == 0) ST_RLX(anchors + 0, 0);

    float bv = -3.3e38f; int bi = 0x7fffffff;
#pragma unroll
    for (int k = 0; k < PPT; ++k) {
      int i = gtid + k * STRIDE;
      bool bt = (md[k] > bv) || (md[k] == bv && i < bi);
      bv = bt ? md[k] : bv; bi = bt ? i : bi;
    }

    int nsel  = 1;
    int batch = 0;
#pragma unroll 1
    while (nsel < N_ANCH) {
      batch++;
      const int par = batch & 1;

      // ---- per-wave top-8 extraction: two-phase DPP, no ballot/readlane ---
      unsigned cons = 0;
      unsigned pkey = 0; int pix = 0;
#pragma unroll 1
      for (int r = 0; r < TW; ++r) {
        unsigned k = key32f(bv);
        unsigned M = wave_umax_dpp(k);
        unsigned cand = (k == M) ? ~(unsigned)bi : 0u;   // max(~bi) = min bi
        unsigned L = wave_umax_dpp(cand);
        int widx = (int)~L;
        if (lane == r) { pkey = M; pix = widx; }
        if (k == M && bi == widx && bi != 0x7fffffff) {  // consuming lane
          cons |= 1u << ((unsigned)(bi - gtid) >> 12);   // STRIDE = 2^12
          bv = -3.3e38f; bi = 0x7fffffff;
#pragma unroll
          for (int kk = 0; kk < PPT; ++kk) {
            if (!((cons >> kk) & 1u)) {
              int i = gtid + kk * STRIDE;
              bool bt = (md[kk] > bv) || (md[kk] == bv && i < bi);
              bv = bt ? md[kk] : bv; bi = bt ? i : bi;
            }
          }
        }
      }

      // ---- publish: ONE batched wave-level store (8 lanes, 64B coalesced);
      //      R12 lesson: never spread agent-scope stores. ----
      if (lane < TW) {
        ST_RLX(&slots[par * POOL + gw * TW + lane], pack_key32(pkey, pix));
      }
      if (lane == 0) ST_REL(flag + gw, batch);   // s_waitcnt vmcnt(0) + store

      // ---- poll all 64 wave-flags: ONE 4B load per lane ----
      for (;;) {
        int f0 = LD_RLX(flag + lane);
        if (__ballot(f0 >= batch) == ~0ull) break;
        __builtin_amdgcn_s_sleep(1);
      }
      __builtin_amdgcn_sched_barrier(0);   // no compiler motion across the poll

      // ---- readback pool ONCE: packed u64 x 8 entries/lane ----
      ull pk[RSLOTS];
#pragma unroll
      for (int j = 0; j < RSLOTS; ++j)
        pk[j] = LD_RLX(&slots[par * POOL + lane + 64 * j]);

      // ---- bucket keys; Mkey (global max bucket) and BmaxKey ----
      // entry e = lane + 64*j; e % 8 == lane % 8, so lanes with (lane&7)==7
      // hold exactly the 8th-published entries of all waves.
      unsigned kj[RSLOTS];
      unsigned lkmax = 0;
#pragma unroll
      for (int j = 0; j < RSLOTS; ++j) {
        kj[j] = (unsigned)(pk[j] >> 32);
        lkmax = (kj[j] > lkmax) ? kj[j] : lkmax;
      }
      const unsigned Mkey    = wave_umax_dpp(lkmax);
      const unsigned BmaxKey = wave_umax_dpp(((lane & 7) == 7) ? lkmax : 0u);

      int cap = N_ANCH - nsel;
      int S = 0;

      if (Mkey > BmaxKey) {
        // -------- typical path: compact live entries (key32 > BmaxKey) -----
        // each wave's own 8th entry <= BmaxKey -> <= 7 live/wave -> <= 448.
        // compacted key layout: key32<<32 | (0xFFFF-idx)<<16 | rank
        int base = 0;
#pragma unroll
        for (int j = 0; j < RSLOTS; ++j) {
          bool live = kj[j] > BmaxKey;
          ull bal = __ballot(live);
          int rank = base + (int)__popcll(bal & ((1ull << lane) - 1ull));
          if (live) {
            sm.f.lv[rank] = (pk[j] & 0xFFFFFFFF00000000ull)
                          | ((pk[j] & 0xFFFFull) << 16) | (ull)(unsigned)rank;
            int p = 0xFFFF - (int)(pk[j] & 0xFFFFull);
            sm.f.lc[rank][0] = pos[3 * p];
            sm.f.lc[rank][1] = pos[3 * p + 1];
            sm.f.lc[rank][2] = pos[3 * p + 2];
          }
          base += (int)__popcll(bal);
        }
        const int live_n = base;   // wave-uniform, 1..448

        // load compaction data to registers (guarded: only active 64-blocks)
        ull pk2[CCAP]; float c2x[CCAP], c2y[CCAP], c2z[CCAP];
#pragma unroll
        for (int tt = 0; tt < CCAP; ++tt) {
          if (live_n > tt * 64) {
            int e = tt * 64 + lane;
            bool ok = e < live_n;
            ull    v  = sm.f.lv[e];
            float  x  = sm.f.lc[e][0];
            float  y  = sm.f.lc[e][1];
            float  z  = sm.f.lc[e][2];
            pk2[tt] = ok ? v : 0ull;
            c2x[tt] = ok ? x : 0.0f;
            c2y[tt] = ok ? y : 0.0f;
            c2z[tt] = ok ? z : 0.0f;
          } else {
            pk2[tt] = 0ull;
            c2x[tt] = 0.0f; c2y[tt] = 0.0f; c2z[tt] = 0.0f;
          }
        }

        // ---- S-loop: zero-ballot zero-readlane chain; md inline (R4) ----
#pragma unroll 1
        while (S < cap) {
          // in-lane max over active packed keys (typ. 1-2 blocks)
          ull wpk = pk2[0];
#pragma unroll
          for (int tt = 1; tt < CCAP; ++tt)
            if (live_n > tt * 64)
              wpk = (pk2[tt] > wpk) ? pk2[tt] : wpk;

          // phase 1: wave max of value key (hi32)
          unsigned hi = (unsigned)(wpk >> 32);
          unsigned M  = wave_umax_dpp(hi);
          if (S != 0 && !(M > BmaxKey)) break;
          // phase 2: among value-max holders, max lo32 = (idx-asc, rank)
          unsigned lo = (hi == M) ? (unsigned)wpk : 0u;
          unsigned L  = wave_umax_dpp(lo);
          ull full = ((ull)M << 32) | (ull)L;
          int widx = 0xFFFF - (int)((L >> 16) & 0xFFFFu);
          int rank = (int)(L & 0xFFFFu);
          float wx = sm.f.lc[rank][0];    // broadcast LDS read (no conflict)
          float wy = sm.f.lc[rank][1];
          float wz = sm.f.lc[rank][2];
          if (gw == 0 && lane == 0) ST_RLX(anchors + nsel + S, widx);

          // update packed keys: u64 min vs new-anchor distance key (low32
          // preserved: idx+rank). Winner dies (-> 0); dead slots stay 0.
#pragma unroll
          for (int tt = 0; tt < CCAP; ++tt) {
            if (live_n > tt * 64) {
              float d = dist32(c2x[tt], c2y[tt], c2z[tt], wx, wy, wz);
              ull dpk = ((ull)key32f(d) << 32) | (pk2[tt] & 0xFFFFFFFFull);
              ull nv  = (dpk < pk2[tt]) ? dpk : pk2[tt];
              pk2[tt] = (pk2[tt] == full) ? 0ull : nv;
            }
          }
          // inline apply to own md slice (bubble-filler under the chain)
#pragma unroll
          for (int k2 = 0; k2 < PPT; ++k2)
            md[k2] = fminf(md[k2], dist32(pdx[k2], pdy[k2], pdz[k2], wx, wy, wz));
          S++;
        }
      } else {
        // -------- fallback (bucket tie at Bmax; rare): packed-exact loop ----
#pragma unroll 1
        while (S < cap) {
          ull wpk = pk[0];
#pragma unroll
          for (int j = 1; j < RSLOTS; ++j) wpk = (pk[j] > wpk) ? pk[j] : wpk;
          ull g = wpk;
#pragma unroll
          for (int off = 1; off < 64; off <<= 1) {
            ull o = __shfl_xor(g, off);
            g = (o > g) ? o : g;
          }
          unsigned wkey = (unsigned)(g >> 32);
          if (S != 0 && !(wkey > BmaxKey)) break;
          int widx = 0xFFFF - (int)(g & 0xFFFFull);
          if (widx < 0) widx = 0;                      // sentinel clamp
          if (widx >= N_PTS) widx = N_PTS - 1;
          float wx = pos[3 * widx];
          float wy = pos[3 * widx + 1];
          float wz = pos[3 * widx + 2];
          if (gw == 0 && lane == 0) ST_RLX(anchors + nsel + S, widx);
#pragma unroll
          for (int j = 0; j < RSLOTS; ++j) {
            int p = 0xFFFF - (int)(pk[j] & 0xFFFFull);
            if (p < 0) p = 0;
            if (p >= N_PTS) p = N_PTS - 1;
            float d = dist32(pos[3 * p], pos[3 * p + 1], pos[3 * p + 2], wx, wy, wz);
            ull dpk = ((ull)key32f(d) << 32) | (pk[j] & 0xFFFFull);
            ull nv  = (dpk < pk[j]) ? dpk : pk[j];
            pk[j] = (pk[j] == g) ? 0ull : nv;
          }
#pragma unroll
          for (int k2 = 0; k2 < PPT; ++k2)
            md[k2] = fminf(md[k2], dist32(pdx[k2], pdy[k2], pdz[k2], wx, wy, wz));
          S++;
        }
      }
      nsel += S;

      // refresh thread-local argmax
      bv = -3.3e38f; bi = 0x7fffffff;
#pragma unroll
      for (int k = 0; k < PPT; ++k) {
        int i = gtid + k * STRIDE;
        bool bt = (md[k] > bv) || (md[k] == bv && i < bi);
        bv = bt ? md[k] : bv; bi = bt ? i : bi;
      }
    }
  } else {
    // =============== KNN: one wave per anchor (no barriers) ===============
    const int aidx = blockIdx.x - NFB;
    int a = -1;
    for (;;) {
      if (lane == 0) a = LD_RLX(anchors + aidx);
      a = __shfl(a, 0);
      if (a >= 0) break;
      __builtin_amdgcn_s_sleep(32);
    }
    const int ai = a;
    const float ax = pos[3 * ai], ay = pos[3 * ai + 1], az = pos[3 * ai + 2];

    // per-lane top-20 (u64 keys, static indexing ONLY -> stays in VGPRs)
    ull key[KNN];
#pragma unroll
    for (int s = 0; s < KNN; ++s) key[s] = ~0ull;
    ull kmax = ~0ull; int smax = 0;
#pragma unroll 1
    for (int k = 0; k < N_PTS / 64; ++k) {   // 625 candidates per lane, exact
      int j = (k << 6) + lane;
      float dx = pos[3 * j] - ax, dy = pos[3 * j + 1] - ay, dz = pos[3 * j + 2] - az;
      float d  = dx * dx + dy * dy + dz * dz;
      ull nk = ((ull)__float_as_uint(d) << 32) | (unsigned)j;
      if (nk < kmax) {
#pragma unroll
        for (int s = 0; s < KNN; ++s) key[s] = (s == smax) ? nk : key[s];
        kmax = 0ull; smax = 0;
#pragma unroll
        for (int s = 0; s < KNN; ++s) {
          bool g = key[s] > kmax;
          kmax = g ? key[s] : kmax;
          smax = g ? s : smax;
        }
      }
    }

    // wave-wide merge: 20 extract-min rounds (shuffle butterfly, no LDS sync)
    ull lmin = ~0ull; int ls = 0;
#pragma unroll
    for (int s = 0; s < KNN; ++s) {
      bool l = key[s] < lmin;
      lmin = l ? key[s] : lmin; ls = l ? s : ls;
    }
#pragma unroll 1
    for (int r = 0; r < KNN; ++r) {
      ull g = lmin;
#pragma unroll
      for (int off = 1; off < 64; off <<= 1) {
        ull ov = __shfl_xor(g, off);
        g = (ov < g) ? ov : g;
      }
      if (lane == 0) sm.k.w[r] = (int)(g & 0xffffffffull);
      if (lmin == g) {          // unique owner consumes & rescans (all static)
#pragma unroll
        for (int s = 0; s < KNN; ++s) key[s] = (s == ls) ? ~0ull : key[s];
        lmin = ~0ull; ls = 0;
#pragma unroll
        for (int s = 0; s < KNN; ++s) {
          bool l = key[s] < lmin;
          lmin = l ? key[s] : lmin; ls = l ? s : ls;
        }
      }
    }

    if (lane == 0) {
      double mx = 0, my = 0, mz = 0;
      for (int r = 0; r < KNN; ++r) {
        int p = sm.k.w[r];
        mx += (double)pos[3 * p]; my += (double)pos[3 * p + 1]; mz += (double)pos[3 * p + 2];
      }
      mx /= KNN; my /= KNN; mz /= KNN;
      double xx = 0, xy = 0, xz = 0, yy = 0, yz = 0, zz = 0;
      for (int r = 0; r < KNN; ++r) {
        int p = sm.k.w[r];
        double cx = (double)pos[3 * p]     - mx;
        double cy = (double)pos[3 * p + 1] - my;
        double cz = (double)pos[3 * p + 2] - mz;
        xx += cx * cx; xy += cx * cy; xz += cx * cz;
        yy += cy * cy; yz += cy * cz; zz += cz * cz;
      }
      double v0, v1, v2;
      eig3_maxvec(xx, xy, xz, yy, yz, zz, v0, v1, v2);

      double a0 = vec_pred[3 * aidx], a1 = vec_pred[3 * aidx + 1], a2 = vec_pred[3 * aidx + 2];
      double an = sqrt(a0 * a0 + a1 * a1 + a2 * a2);
      double bn = sqrt(v0 * v0 + v1 * v1 + v2 * v2);
      double denom = fmax(an, 1e-8) * fmax(bn, 1e-8);
      double c = fabs((a0 * v0 + a1 * v1 + a2 * v2) / denom);
      atomicAdd(acc, log(c + 1e-6));
    }
  }
}

__global__ void finalize_kernel(const double* __restrict__ acc, float* __restrict__ out) {
  out[0] = (float)(-acc[0] / (double)N_ANCH);
}

// ===========================================================================
extern "C" void kernel_launch(void* const* d_in, const int* in_sizes, int n_in,
                              void* d_out, int out_size, void* d_ws, size_t ws_size,
                              hipStream_t stream) {
  (void)in_sizes; (void)n_in; (void)out_size; (void)ws_size;
  const float* vec_pred = (const float*)d_in[0];
  const float* pos      = (const float*)d_in[1];
  float* out = (float*)d_out;

  char* ws = (char*)d_ws;
  double* acc     = (double*)(ws + 0);
  int*    flag    = (int*)(ws + 64);
  ull*    slots   = (ull*)(ws + 1024);
  int*    anchors = (int*)(ws + 17408);

  hipMemsetAsync(ws, 0, 1024, stream);                   // acc + flags
  hipMemsetAsync(ws + 17408, 0xFF, N_ANCH * 4, stream);  // anchors = -1
  hipLaunchKernelGGL(fps_knn_kernel, dim3(NFB + N_ANCH), dim3(BT), 0, stream,
                     pos, vec_pred, flag, slots, anchors, acc);
  hipLaunchKernelGGL(finalize_kernel, dim3(1), dim3(1), 0, stream, acc, out);
}

// Round 14
// 2803.764 us; speedup vs baseline: 1.3891x; 1.1791x over previous
//
#include <hip/hip_runtime.h>
#include <math.h>

#define N_PTS       40000
#define N_ANCH      4000     // ceil(0.1 * 40000)
#define KNN         20
#define NFB         128      // fps blocks (1 wave each)
#define BT          64       // threads per block (all blocks) = 1 wave
#define NWAVES      128                // fps waves
#define STRIDE      (NWAVES * 64)      // 8192 = 2^13
#define PPT         5                  // 8192*5 = 40960 >= 40000
#define TW          4                  // published candidates per WAVE
#define POOL        (NWAVES * TW)      // 512
#define RSLOTS      (POOL / 64)        // 8 readback entries per lane
#define CCAP        6                  // compacted capacity/lane (384 hard bound)

// (TW, NWAVES) sweep is DONE: (4,128) optimal. TW=8@128w: alpha blows up via
// live-set chain + extraction (R11). TW=8@64w: alpha blows up via PPT=10 md
// work exceeding chain bubbles (R13). C~7us is a latency floor (R12/R13).

typedef unsigned long long ull;

#define LD_RLX(p)    __hip_atomic_load((p),  __ATOMIC_RELAXED, __HIP_MEMORY_SCOPE_AGENT)
#define ST_REL(p,v)  __hip_atomic_store((p), (v), __ATOMIC_RELEASE, __HIP_MEMORY_SCOPE_AGENT)
#define ST_RLX(p,v)  __hip_atomic_store((p), (v), __ATOMIC_RELAXED, __HIP_MEMORY_SCOPE_AGENT)

// Workspace layout (identical to R10):
//   off     0 : double acc               (zeroed)
//   off    64 : int flag[128]            (zeroed; per-wave monotone batch counters)
//   off  1024 : ull slots[2][512]        (parity x pool, packed {key32|idx16}; 8 KB)
//   off 17408 : int anchors[4000]        (memset 0xFF -> -1)

__device__ __forceinline__ float dist32(float px, float py, float pz,
                                        float wx, float wy, float wz) {
  float dx = px - wx, dy = py - wy, dz = pz - wz;
  return dx * dx + dy * dy + dz * dz;
}

// monotone u32 key from f32 (exact order embedding)
__device__ __forceinline__ unsigned key32f(float v) {
  unsigned b = __float_as_uint(v);
  return (b & 0x80000000u) ? ~b : (b | 0x80000000u);
}

// published slot: (value-desc, idx-asc) as ONE u64.
__device__ __forceinline__ ull pack_key32(unsigned key, int idx) {
  return ((ull)key << 32) | (ull)((0xFFFF - idx) & 0xFFFF);
}

// wave-wide max of u32 via DPP (VALU only); returns wave-uniform max
__device__ __forceinline__ unsigned wave_umax_dpp(unsigned x) {
#define DPP_STEP(ctrl) { unsigned y = (unsigned)__builtin_amdgcn_update_dpp( \
      0, (int)x, ctrl, 0xf, 0xf, true); x = (y > x) ? y : x; }
  DPP_STEP(0x111)  // row_shr:1
  DPP_STEP(0x112)  // row_shr:2
  DPP_STEP(0x114)  // row_shr:4
  DPP_STEP(0x118)  // row_shr:8
  DPP_STEP(0x142)  // row_bcast:15
  DPP_STEP(0x143)  // row_bcast:31
#undef DPP_STEP
  return (unsigned)__builtin_amdgcn_readlane((int)x, 63);
}

struct FpsSm {                 // single-wave compaction buffers (7680 B)
  ull    lv[CCAP * 64];        // packed keys (with rank in low 16)
  float  lc[CCAP * 64][3];     // coords indexed by rank
};
struct KnnSm { int w[KNN]; };
union Smem { FpsSm f; KnnSm k; };

// ============== symmetric 3x3: eigenvector of largest eigenvalue ===========
__device__ static inline void eig3_maxvec(double xx, double xy, double xz,
                                          double yy, double yz, double zz,
                                          double& v0, double& v1, double& v2) {
  double q  = (xx + yy + zz) / 3.0;
  double p1 = xy * xy + xz * xz + yz * yz;
  double a00 = xx - q, a11 = yy - q, a22 = zz - q;
  double p2 = a00 * a00 + a11 * a11 + a22 * a22 + 2.0 * p1;
  if (p2 < 1e-300) { v0 = 1.0; v1 = 0.0; v2 = 0.0; return; }
  double p   = sqrt(p2 / 6.0);
  double inv = 1.0 / p;
  double b00 = a00 * inv, b01 = xy * inv, b02 = xz * inv;
  double b11 = a11 * inv, b12 = yz * inv, b22 = a22 * inv;
  double detB = b00 * (b11 * b22 - b12 * b12)
              - b01 * (b01 * b22 - b12 * b02)
              + b02 * (b01 * b12 - b11 * b02);
  double r = fmin(1.0, fmax(-1.0, detB * 0.5));
  double phi = acos(r) / 3.0;
  double lam = q + 2.0 * p * cos(phi);   // largest eigenvalue

  double r0x = xx - lam, r0y = xy,       r0z = xz;
  double r1x = xy,       r1y = yy - lam, r1z = yz;
  double r2x = xz,       r2y = yz,       r2z = zz - lam;
  double c0x = r0y * r1z - r0z * r1y, c0y = r0z * r1x - r0x * r1z, c0z = r0x * r1y - r0y * r1x;
  double c1x = r0y * r2z - r0z * r2y, c1y = r0z * r2x - r0x * r2z, c1z = r0x * r2y - r0y * r2x;
  double c2x = r1y * r2z - r1z * r2y, c2y = r1z * r2x - r1x * r2z, c2z = r1x * r2y - r1y * r2x;
  double n0 = c0x * c0x + c0y * c0y + c0z * c0z;
  double n1 = c1x * c1x + c1y * c1y + c1z * c1z;
  double n2 = c2x * c2x + c2y * c2y + c2z * c2z;
  double bx = c0x, by = c0y, bz = c0z, bn = n0;
  if (n1 > bn) { bx = c1x; by = c1y; bz = c1z; bn = n1; }
  if (n2 > bn) { bx = c2x; by = c2y; bz = c2z; bn = n2; }
  if (bn < 1e-280) { v0 = 1.0; v1 = 0.0; v2 = 0.0; return; }
  double s = 1.0 / sqrt(bn);
  v0 = bx * s; v1 = by * s; v2 = bz * s;
}

// ===========================================================================
__global__ __launch_bounds__(BT, 2) void fps_knn_kernel(
    const float* __restrict__ pos, const float* __restrict__ vec_pred,
    int* __restrict__ flag, ull* __restrict__ slots,
    int* __restrict__ anchors, double* __restrict__ acc) {
  __shared__ Smem sm;
  const int lane = threadIdx.x & 63;

  if (blockIdx.x < NFB) {
    // ============ FPS: one wave per block, wave-autonomous ================
    __builtin_amdgcn_s_setprio(1);   // FPS is the critical path (R0: +2-3%)

    const int gw   = blockIdx.x;       // global wave id, 0..127
    const int gtid = gw * 64 + lane;

    float pdx[PPT], pdy[PPT], pdz[PPT], md[PPT];   // f32 coords + min-dist
    const float a0x = pos[0], a0y = pos[1], a0z = pos[2];
#pragma unroll
    for (int k = 0; k < PPT; ++k) {
      int i = gtid + k * STRIDE;
      if (i < N_PTS) {
        pdx[k] = pos[3 * i];
        pdy[k] = pos[3 * i + 1];
        pdz[k] = pos[3 * i + 2];
        md[k]  = dist32(pdx[k], pdy[k], pdz[k], a0x, a0y, a0z);
      } else {
        pdx[k] = 0.0f; pdy[k] = 0.0f; pdz[k] = 0.0f;
        md[k]  = -3.0e38f;   // pad: never beats real md >= 0
      }
    }
    if (gw == 0 && lane == 0) ST_RLX(anchors + 0, 0);

    float bv = -3.3e38f; int bi = 0x7fffffff;
#pragma unroll
    for (int k = 0; k < PPT; ++k) {
      int i = gtid + k * STRIDE;
      bool bt = (md[k] > bv) || (md[k] == bv && i < bi);
      bv = bt ? md[k] : bv; bi = bt ? i : bi;
    }

    int nsel  = 1;
    int batch = 0;
#pragma unroll 1
    while (nsel < N_ANCH) {
      batch++;
      const int par = batch & 1;

      // ---- per-wave top-4 extraction: two-phase DPP, no ballot/readlane ---
      unsigned cons = 0;
      unsigned pkey = 0; int pix = 0;
#pragma unroll 1
      for (int r = 0; r < TW; ++r) {
        unsigned k = key32f(bv);
        unsigned M = wave_umax_dpp(k);
        unsigned cand = (k == M) ? ~(unsigned)bi : 0u;   // max(~bi) = min bi
        unsigned L = wave_umax_dpp(cand);
        int widx = (int)~L;
        if (lane == r) { pkey = M; pix = widx; }
        if (k == M && bi == widx && bi != 0x7fffffff) {  // consuming lane
          cons |= 1u << ((unsigned)(bi - gtid) >> 13);   // STRIDE = 2^13
          bv = -3.3e38f; bi = 0x7fffffff;
#pragma unroll
          for (int kk = 0; kk < PPT; ++kk) {
            if (!((cons >> kk) & 1u)) {
              int i = gtid + kk * STRIDE;
              bool bt = (md[kk] > bv) || (md[kk] == bv && i < bi);
              bv = bt ? md[kk] : bv; bi = bt ? i : bi;
            }
          }
        }
      }

      // ---- publish: ONE batched wave-level store (R12 lesson) ----
      if (lane < TW) {
        ST_RLX(&slots[par * POOL + gw * TW + lane], pack_key32(pkey, pix));
      }
      if (lane == 0) ST_REL(flag + gw, batch);   // s_waitcnt vmcnt(0) + store

      // ---- poll all 128 wave-flags: ONE paired 8B load per lane ----------
      {
        const ull* flag2 = (const ull*)flag;
        for (;;) {
          ull f = LD_RLX(flag2 + lane);
          int f0 = (int)(unsigned)(f & 0xffffffffull);
          int f1 = (int)(unsigned)(f >> 32);
          if (__ballot((f0 >= batch) && (f1 >= batch)) == ~0ull) break;
          __builtin_amdgcn_s_sleep(1);
        }
      }
      __builtin_amdgcn_sched_barrier(0);   // no compiler motion across the poll

      // ---- readback pool ONCE: packed u64 x 8 entries/lane ----
      ull pk[RSLOTS];
#pragma unroll
      for (int j = 0; j < RSLOTS; ++j)
        pk[j] = LD_RLX(&slots[par * POOL + lane + 64 * j]);

      // ---- bucket keys; Mkey (global max bucket) and BmaxKey ----
      unsigned kj[RSLOTS];
      unsigned lkmax = 0;
#pragma unroll
      for (int j = 0; j < RSLOTS; ++j) {
        kj[j] = (unsigned)(pk[j] >> 32);
        lkmax = (kj[j] > lkmax) ? kj[j] : lkmax;
      }
      const unsigned Mkey    = wave_umax_dpp(lkmax);
      const unsigned BmaxKey = wave_umax_dpp(((lane & 3) == 3) ? lkmax : 0u);

      int cap = N_ANCH - nsel;
      int S = 0;

      if (Mkey > BmaxKey) {
        // -------- typical path: compact live entries (key32 > BmaxKey) -----
        // compacted key layout: key32<<32 | (0xFFFF-idx)<<16 | rank
        int base = 0;
#pragma unroll
        for (int j = 0; j < RSLOTS; ++j) {
          bool live = kj[j] > BmaxKey;
          ull bal = __ballot(live);
          int rank = base + (int)__popcll(bal & ((1ull << lane) - 1ull));
          if (live) {
            sm.f.lv[rank] = (pk[j] & 0xFFFFFFFF00000000ull)
                          | ((pk[j] & 0xFFFFull) << 16) | (ull)(unsigned)rank;
            int p = 0xFFFF - (int)(pk[j] & 0xFFFFull);
            sm.f.lc[rank][0] = pos[3 * p];
            sm.f.lc[rank][1] = pos[3 * p + 1];
            sm.f.lc[rank][2] = pos[3 * p + 2];
          }
          base += (int)__popcll(bal);
        }
        const int live_n = base;   // wave-uniform, 1..384

        // load compaction data to registers (packed key + f32 coords)
        ull pk2[CCAP]; float c2x[CCAP], c2y[CCAP], c2z[CCAP];
#pragma unroll
        for (int tt = 0; tt < CCAP; ++tt) {
          if (live_n > tt * 64) {
            int e = tt * 64 + lane;
            bool ok = e < live_n;
            ull    v  = sm.f.lv[e];
            float  x  = sm.f.lc[e][0];
            float  y  = sm.f.lc[e][1];
            float  z  = sm.f.lc[e][2];
            pk2[tt] = ok ? v : 0ull;
            c2x[tt] = ok ? x : 0.0f;
            c2y[tt] = ok ? y : 0.0f;
            c2z[tt] = ok ? z : 0.0f;
          } else {
            pk2[tt] = 0ull;
            c2x[tt] = 0.0f; c2y[tt] = 0.0f; c2z[tt] = 0.0f;
          }
        }

        // ---- S-loop: zero-ballot zero-readlane chain; md inline (R4).
        // Wave 0 STASHES anchors in lane-sliced registers (static chunk
        // index, rule #20) and emits ONE coalesced burst after the loop:
        // removes per-selection coherent stores from gw0's publish drain
        // (the per-batch straggler). S <= live_n <= 384 -> 6 chunks.
        int sa0 = 0, sa1 = 0, sa2 = 0, sa3 = 0, sa4 = 0, sa5 = 0;
#pragma unroll 1
        while (S < cap) {
          // in-lane max over 6 packed keys
          ull wpk = pk2[0];
#pragma unroll
          for (int tt = 1; tt < CCAP; ++tt)
            wpk = (pk2[tt] > wpk) ? pk2[tt] : wpk;

          // phase 1: wave max of value key (hi32)
          unsigned hi = (unsigned)(wpk >> 32);
          unsigned M  = wave_umax_dpp(hi);
          if (S != 0 && !(M > BmaxKey)) break;
          // phase 2: among value-max holders, max lo32 = (idx-asc, rank)
          unsigned lo = (hi == M) ? (unsigned)wpk : 0u;
          unsigned L  = wave_umax_dpp(lo);
          ull full = ((ull)M << 32) | (ull)L;
          int widx = 0xFFFF - (int)((L >> 16) & 0xFFFFu);
          int rank = (int)(L & 0xFFFFu);
          float wx = sm.f.lc[rank][0];    // broadcast LDS read (no conflict)
          float wy = sm.f.lc[rank][1];
          float wz = sm.f.lc[rank][2];
          if (gw == 0 && lane == (S & 63)) {   // stash (static chunk select)
            int j = S >> 6;
            if      (j == 0) sa0 = widx;
            else if (j == 1) sa1 = widx;
            else if (j == 2) sa2 = widx;
            else if (j == 3) sa3 = widx;
            else if (j == 4) sa4 = widx;
            else             sa5 = widx;
          }

          // update packed keys: u64 min vs new-anchor distance key (low32
          // preserved: idx+rank). Winner dies (-> 0); dead slots stay 0.
#pragma unroll
          for (int tt = 0; tt < CCAP; ++tt) {
            if (live_n > tt * 64) {
              float d = dist32(c2x[tt], c2y[tt], c2z[tt], wx, wy, wz);
              ull dpk = ((ull)key32f(d) << 32) | (pk2[tt] & 0xFFFFFFFFull);
              ull nv  = (dpk < pk2[tt]) ? dpk : pk2[tt];
              pk2[tt] = (pk2[tt] == full) ? 0ull : nv;
            }
          }
          // inline apply to own md slice (bubble-filler under the chain)
#pragma unroll
          for (int k2 = 0; k2 < PPT; ++k2)
            md[k2] = fminf(md[k2], dist32(pdx[k2], pdy[k2], pdz[k2], wx, wy, wz));
          S++;
        }

        // coalesced anchor burst (drains during refresh + next extraction)
        if (gw == 0) {
          if (S > 0   && lane < S)       ST_RLX(anchors + nsel + lane, sa0);
          if (S > 64  && lane < S - 64)  ST_RLX(anchors + nsel + 64  + lane, sa1);
          if (S > 128 && lane < S - 128) ST_RLX(anchors + nsel + 128 + lane, sa2);
          if (S > 192 && lane < S - 192) ST_RLX(anchors + nsel + 192 + lane, sa3);
          if (S > 256 && lane < S - 256) ST_RLX(anchors + nsel + 256 + lane, sa4);
          if (S > 320 && lane < S - 320) ST_RLX(anchors + nsel + 320 + lane, sa5);
        }
      } else {
        // -------- fallback (bucket tie at Bmax; rare): packed-exact loop ----
#pragma unroll 1
        while (S < cap) {
          ull wpk = pk[0];
#pragma unroll
          for (int j = 1; j < RSLOTS; ++j) wpk = (pk[j] > wpk) ? pk[j] : wpk;
          ull g = wpk;
#pragma unroll
          for (int off = 1; off < 64; off <<= 1) {
            ull o = __shfl_xor(g, off);
            g = (o > g) ? o : g;
          }
          unsigned wkey = (unsigned)(g >> 32);
          if (S != 0 && !(wkey > BmaxKey)) break;
          int widx = 0xFFFF - (int)(g & 0xFFFFull);
          if (widx < 0) widx = 0;                      // sentinel clamp
          if (widx >= N_PTS) widx = N_PTS - 1;
          float wx = pos[3 * widx];
          float wy = pos[3 * widx + 1];
          float wz = pos[3 * widx + 2];
          if (gw == 0 && lane == 0) ST_RLX(anchors + nsel + S, widx);
#pragma unroll
          for (int j = 0; j < RSLOTS; ++j) {
            int p = 0xFFFF - (int)(pk[j] & 0xFFFFull);
            if (p < 0) p = 0;
            if (p >= N_PTS) p = N_PTS - 1;
            float d = dist32(pos[3 * p], pos[3 * p + 1], pos[3 * p + 2], wx, wy, wz);
            ull dpk = ((ull)key32f(d) << 32) | (pk[j] & 0xFFFFull);
            ull nv  = (dpk < pk[j]) ? dpk : pk[j];
            pk[j] = (pk[j] == g) ? 0ull : nv;
          }
#pragma unroll
          for (int k2 = 0; k2 < PPT; ++k2)
            md[k2] = fminf(md[k2], dist32(pdx[k2], pdy[k2], pdz[k2], wx, wy, wz));
          S++;
        }
      }
      nsel += S;

      // refresh thread-local argmax
      bv = -3.3e38f; bi = 0x7fffffff;
#pragma unroll
      for (int k = 0; k < PPT; ++k) {
        int i = gtid + k * STRIDE;
        bool bt = (md[k] > bv) || (md[k] == bv && i < bi);
        bv = bt ? md[k] : bv; bi = bt ? i : bi;
      }
    }
  } else {
    // =============== KNN: one wave per anchor (no barriers) ===============
    const int aidx = blockIdx.x - NFB;
    int a = -1;
    for (;;) {
      if (lane == 0) a = LD_RLX(anchors + aidx);
      a = __shfl(a, 0);
      if (a >= 0) break;
      __builtin_amdgcn_s_sleep(32);
    }
    const int ai = a;
    const float ax = pos[3 * ai], ay = pos[3 * ai + 1], az = pos[3 * ai + 2];

    // per-lane top-20 (u64 keys, static indexing ONLY -> stays in VGPRs)
    ull key[KNN];
#pragma unroll
    for (int s = 0; s < KNN; ++s) key[s] = ~0ull;
    ull kmax = ~0ull; int smax = 0;
#pragma unroll 1
    for (int k = 0; k < N_PTS / 64; ++k) {   // 625 candidates per lane, exact
      int j = (k << 6) + lane;
      float dx = pos[3 * j] - ax, dy = pos[3 * j + 1] - ay, dz = pos[3 * j + 2] - az;
      float d  = dx * dx + dy * dy + dz * dz;
      ull nk = ((ull)__float_as_uint(d) << 32) | (unsigned)j;
      if (nk < kmax) {
#pragma unroll
        for (int s = 0; s < KNN; ++s) key[s] = (s == smax) ? nk : key[s];
        kmax = 0ull; smax = 0;
#pragma unroll
        for (int s = 0; s < KNN; ++s) {
          bool g = key[s] > kmax;
          kmax = g ? key[s] : kmax;
          smax = g ? s : smax;
        }
      }
    }

    // wave-wide merge: 20 extract-min rounds (shuffle butterfly, no LDS sync)
    ull lmin = ~0ull; int ls = 0;
#pragma unroll
    for (int s = 0; s < KNN; ++s) {
      bool l = key[s] < lmin;
      lmin = l ? key[s] : lmin; ls = l ? s : ls;
    }
#pragma unroll 1
    for (int r = 0; r < KNN; ++r) {
      ull g = lmin;
#pragma unroll
      for (int off = 1; off < 64; off <<= 1) {
        ull ov = __shfl_xor(g, off);
        g = (ov < g) ? ov : g;
      }
      if (lane == 0) sm.k.w[r] = (int)(g & 0xffffffffull);
      if (lmin == g) {          // unique owner consumes & rescans (all static)
#pragma unroll
        for (int s = 0; s < KNN; ++s) key[s] = (s == ls) ? ~0ull : key[s];
        lmin = ~0ull; ls = 0;
#pragma unroll
        for (int s = 0; s < KNN; ++s) {
          bool l = key[s] < lmin;
          lmin = l ? key[s] : lmin; ls = l ? s : ls;
        }
      }
    }

    if (lane == 0) {
      double mx = 0, my = 0, mz = 0;
      for (int r = 0; r < KNN; ++r) {
        int p = sm.k.w[r];
        mx += (double)pos[3 * p]; my += (double)pos[3 * p + 1]; mz += (double)pos[3 * p + 2];
      }
      mx /= KNN; my /= KNN; mz /= KNN;
      double xx = 0, xy = 0, xz = 0, yy = 0, yz = 0, zz = 0;
      for (int r = 0; r < KNN; ++r) {
        int p = sm.k.w[r];
        double cx = (double)pos[3 * p]     - mx;
        double cy = (double)pos[3 * p + 1] - my;
        double cz = (double)pos[3 * p + 2] - mz;
        xx += cx * cx; xy += cx * cy; xz += cx * cz;
        yy += cy * cy; yz += cy * cz; zz += cz * cz;
      }
      double v0, v1, v2;
      eig3_maxvec(xx, xy, xz, yy, yz, zz, v0, v1, v2);

      double a0 = vec_pred[3 * aidx], a1 = vec_pred[3 * aidx + 1], a2 = vec_pred[3 * aidx + 2];
      double an = sqrt(a0 * a0 + a1 * a1 + a2 * a2);
      double bn = sqrt(v0 * v0 + v1 * v1 + v2 * v2);
      double denom = fmax(an, 1e-8) * fmax(bn, 1e-8);
      double c = fabs((a0 * v0 + a1 * v1 + a2 * v2) / denom);
      atomicAdd(acc, log(c + 1e-6));
    }
  }
}

__global__ void finalize_kernel(const double* __restrict__ acc, float* __restrict__ out) {
  out[0] = (float)(-acc[0] / (double)N_ANCH);
}

// ===========================================================================
extern "C" void kernel_launch(void* const* d_in, const int* in_sizes, int n_in,
                              void* d_out, int out_size, void* d_ws, size_t ws_size,
                              hipStream_t stream) {
  (void)in_sizes; (void)n_in; (void)out_size; (void)ws_size;
  const float* vec_pred = (const float*)d_in[0];
  const float* pos      = (const float*)d_in[1];
  float* out = (float*)d_out;

  char* ws = (char*)d_ws;
  double* acc     = (double*)(ws + 0);
  int*    flag    = (int*)(ws + 64);
  ull*    slots   = (ull*)(ws + 1024);
  int*    anchors = (int*)(ws + 17408);

  hipMemsetAsync(ws, 0, 1024, stream);                   // acc + flags
  hipMemsetAsync(ws + 17408, 0xFF, N_ANCH * 4, stream);  // anchors = -1
  hipLaunchKernelGGL(fps_knn_kernel, dim3(NFB + N_ANCH), dim3(BT), 0, stream,
                     pos, vec_pred, flag, slots, anchors, acc);
  hipLaunchKernelGGL(finalize_kernel, dim3(1), dim3(1), 0, stream, acc, out);
}

// Round 15
// 2683.114 us; speedup vs baseline: 1.4515x; 1.0450x over previous
//
#include <hip/hip_runtime.h>
#include <math.h>

#define N_PTS       40000
#define N_ANCH      4000     // ceil(0.1 * 40000)
#define KNN         20
#define NFB         128      // fps blocks (1 wave each)
#define BT          64       // threads per block (all blocks) = 1 wave
#define NWAVES      128                // fps waves
#define STRIDE      (NWAVES * 64)      // 8192 = 2^13
#define PPT         5                  // 8192*5 = 40960 >= 40000
#define TW          4                  // published candidates per WAVE
#define POOL        (NWAVES * TW)      // 512
#define RSLOTS      (POOL / 64)        // 8 readback entries per lane
#define CCAP        6                  // compacted capacity/lane (384 hard bound)

// FINAL CONFIG (R15 = R10 verbatim, best measured 2687us):
// Design-space map from 15 rounds:
//  - (TW,NWAVES)=(4,128) optimal: TW=8@128w inflates alpha via live-set/
//    extraction (R11); TW=8@64w inflates alpha via PPT=10 exceeding chain
//    bubbles (R13).
//  - C ~ 9.7us/batch is a coherence-latency floor: invariant under poller
//    count (R13), traffic volume (R12), XCD placement (R3); grows only
//    under funneling (R3) or gross poll traffic (R7).
//  - alpha ~ 0.2us/selection: f32 keys (R9) + zero-ballot/readlane chain
//    (R10). Work moved OUT of chain bubbles costs (R4, R14); work left
//    inline is free.
//  - Agent-scope stores must be ONE batched wave-level instruction (R12).
// T = 4000*alpha + 194*C ~ 0.8ms + 1.9ms = 2.7ms (measured 2687us).

typedef unsigned long long ull;

#define LD_RLX(p)    __hip_atomic_load((p),  __ATOMIC_RELAXED, __HIP_MEMORY_SCOPE_AGENT)
#define ST_REL(p,v)  __hip_atomic_store((p), (v), __ATOMIC_RELEASE, __HIP_MEMORY_SCOPE_AGENT)
#define ST_RLX(p,v)  __hip_atomic_store((p), (v), __ATOMIC_RELAXED, __HIP_MEMORY_SCOPE_AGENT)

// Workspace layout:
//   off     0 : double acc               (zeroed)
//   off    64 : int flag[128]            (zeroed; per-wave monotone batch counters)
//   off  1024 : ull slots[2][512]        (parity x pool, packed {key32|idx16}; 8 KB)
//   off 17408 : int anchors[4000]        (memset 0xFF -> -1)

__device__ __forceinline__ float dist32(float px, float py, float pz,
                                        float wx, float wy, float wz) {
  float dx = px - wx, dy = py - wy, dz = pz - wz;
  return dx * dx + dy * dy + dz * dz;
}

// monotone u32 key from f32 (exact order embedding)
__device__ __forceinline__ unsigned key32f(float v) {
  unsigned b = __float_as_uint(v);
  return (b & 0x80000000u) ? ~b : (b | 0x80000000u);
}

// published slot: (value-desc, idx-asc) as ONE u64.
//   pk = (key32f(v) << 32) | ((0xFFFF - idx) & 0xFFFF)
__device__ __forceinline__ ull pack_key32(unsigned key, int idx) {
  return ((ull)key << 32) | (ull)((0xFFFF - idx) & 0xFFFF);
}

// wave-wide max of u32 via DPP (VALU only); returns wave-uniform max
__device__ __forceinline__ unsigned wave_umax_dpp(unsigned x) {
#define DPP_STEP(ctrl) { unsigned y = (unsigned)__builtin_amdgcn_update_dpp( \
      0, (int)x, ctrl, 0xf, 0xf, true); x = (y > x) ? y : x; }
  DPP_STEP(0x111)  // row_shr:1
  DPP_STEP(0x112)  // row_shr:2
  DPP_STEP(0x114)  // row_shr:4
  DPP_STEP(0x118)  // row_shr:8
  DPP_STEP(0x142)  // row_bcast:15
  DPP_STEP(0x143)  // row_bcast:31
#undef DPP_STEP
  return (unsigned)__builtin_amdgcn_readlane((int)x, 63);
}

struct FpsSm {                 // single-wave compaction buffers (7680 B)
  ull    lv[CCAP * 64];        // packed keys (with rank in low 16)
  float  lc[CCAP * 64][3];     // coords indexed by rank
};
struct KnnSm { int w[KNN]; };
union Smem { FpsSm f; KnnSm k; };

// ============== symmetric 3x3: eigenvector of largest eigenvalue ===========
__device__ static inline void eig3_maxvec(double xx, double xy, double xz,
                                          double yy, double yz, double zz,
                                          double& v0, double& v1, double& v2) {
  double q  = (xx + yy + zz) / 3.0;
  double p1 = xy * xy + xz * xz + yz * yz;
  double a00 = xx - q, a11 = yy - q, a22 = zz - q;
  double p2 = a00 * a00 + a11 * a11 + a22 * a22 + 2.0 * p1;
  if (p2 < 1e-300) { v0 = 1.0; v1 = 0.0; v2 = 0.0; return; }
  double p   = sqrt(p2 / 6.0);
  double inv = 1.0 / p;
  double b00 = a00 * inv, b01 = xy * inv, b02 = xz * inv;
  double b11 = a11 * inv, b12 = yz * inv, b22 = a22 * inv;
  double detB = b00 * (b11 * b22 - b12 * b12)
              - b01 * (b01 * b22 - b12 * b02)
              + b02 * (b01 * b12 - b11 * b02);
  double r = fmin(1.0, fmax(-1.0, detB * 0.5));
  double phi = acos(r) / 3.0;
  double lam = q + 2.0 * p * cos(phi);   // largest eigenvalue

  double r0x = xx - lam, r0y = xy,       r0z = xz;
  double r1x = xy,       r1y = yy - lam, r1z = yz;
  double r2x = xz,       r2y = yz,       r2z = zz - lam;
  double c0x = r0y * r1z - r0z * r1y, c0y = r0z * r1x - r0x * r1z, c0z = r0x * r1y - r0y * r1x;
  double c1x = r0y * r2z - r0z * r2y, c1y = r0z * r2x - r0x * r2z, c1z = r0x * r2y - r0y * r2x;
  double c2x = r1y * r2z - r1z * r2y, c2y = r1z * r2x - r1x * r2z, c2z = r1x * r2y - r1y * r2x;
  double n0 = c0x * c0x + c0y * c0y + c0z * c0z;
  double n1 = c1x * c1x + c1y * c1y + c1z * c1z;
  double n2 = c2x * c2x + c2y * c2y + c2z * c2z;
  double bx = c0x, by = c0y, bz = c0z, bn = n0;
  if (n1 > bn) { bx = c1x; by = c1y; bz = c1z; bn = n1; }
  if (n2 > bn) { bx = c2x; by = c2y; bz = c2z; bn = n2; }
  if (bn < 1e-280) { v0 = 1.0; v1 = 0.0; v2 = 0.0; return; }
  double s = 1.0 / sqrt(bn);
  v0 = bx * s; v1 = by * s; v2 = bz * s;
}

// ===========================================================================
__global__ __launch_bounds__(BT, 2) void fps_knn_kernel(
    const float* __restrict__ pos, const float* __restrict__ vec_pred,
    int* __restrict__ flag, ull* __restrict__ slots,
    int* __restrict__ anchors, double* __restrict__ acc) {
  __shared__ Smem sm;
  const int lane = threadIdx.x & 63;

  if (blockIdx.x < NFB) {
    // ============ FPS: one wave per block, wave-autonomous ================
    __builtin_amdgcn_s_setprio(1);   // FPS is the critical path (R0: +2-3%)

    const int gw   = blockIdx.x;       // global wave id, 0..127
    const int gtid = gw * 64 + lane;

    float pdx[PPT], pdy[PPT], pdz[PPT], md[PPT];   // f32 coords + min-dist
    const float a0x = pos[0], a0y = pos[1], a0z = pos[2];
#pragma unroll
    for (int k = 0; k < PPT; ++k) {
      int i = gtid + k * STRIDE;
      if (i < N_PTS) {
        pdx[k] = pos[3 * i];
        pdy[k] = pos[3 * i + 1];
        pdz[k] = pos[3 * i + 2];
        md[k]  = dist32(pdx[k], pdy[k], pdz[k], a0x, a0y, a0z);
      } else {
        pdx[k] = 0.0f; pdy[k] = 0.0f; pdz[k] = 0.0f;
        md[k]  = -3.0e38f;   // pad: never beats real md >= 0
      }
    }
    if (gw == 0 && lane == 0) ST_RLX(anchors + 0, 0);

    float bv = -3.3e38f; int bi = 0x7fffffff;
#pragma unroll
    for (int k = 0; k < PPT; ++k) {
      int i = gtid + k * STRIDE;
      bool bt = (md[k] > bv) || (md[k] == bv && i < bi);
      bv = bt ? md[k] : bv; bi = bt ? i : bi;
    }

    int nsel  = 1;
    int batch = 0;
#pragma unroll 1
    while (nsel < N_ANCH) {
      batch++;
      const int par = batch & 1;

      // ---- per-wave top-4 extraction: two-phase DPP, no ballot/readlane ---
      unsigned cons = 0;
      unsigned pkey = 0; int pix = 0;
#pragma unroll 1
      for (int r = 0; r < TW; ++r) {
        unsigned k = key32f(bv);
        unsigned M = wave_umax_dpp(k);
        unsigned cand = (k == M) ? ~(unsigned)bi : 0u;   // max(~bi) = min bi
        unsigned L = wave_umax_dpp(cand);
        int widx = (int)~L;
        if (lane == r) { pkey = M; pix = widx; }
        if (k == M && bi == widx && bi != 0x7fffffff) {  // consuming lane
          cons |= 1u << ((unsigned)(bi - gtid) >> 13);   // STRIDE = 2^13
          bv = -3.3e38f; bi = 0x7fffffff;
#pragma unroll
          for (int kk = 0; kk < PPT; ++kk) {
            if (!((cons >> kk) & 1u)) {
              int i = gtid + kk * STRIDE;
              bool bt = (md[kk] > bv) || (md[kk] == bv && i < bi);
              bv = bt ? md[kk] : bv; bi = bt ? i : bi;
            }
          }
        }
      }

      // ---- publish: ONE packed 8B store/lane; lane0 release flag orders ----
      if (lane < TW) {
        ST_RLX(&slots[par * POOL + gw * TW + lane], pack_key32(pkey, pix));
      }
      if (lane == 0) ST_REL(flag + gw, batch);   // s_waitcnt vmcnt(0) + store

      // ---- poll all 128 wave-flags (minimal footprint: 2 words/lane) -----
      for (;;) {
        int f0 = LD_RLX(flag + lane);
        int f1 = LD_RLX(flag + 64 + lane);
        if (__ballot((f0 >= batch) && (f1 >= batch)) == ~0ull) break;
        __builtin_amdgcn_s_sleep(1);
      }
      __builtin_amdgcn_sched_barrier(0);   // no compiler motion across the poll

      // ---- readback pool ONCE: packed u64 x 8 entries/lane ----
      ull pk[RSLOTS];
#pragma unroll
      for (int j = 0; j < RSLOTS; ++j)
        pk[j] = LD_RLX(&slots[par * POOL + lane + 64 * j]);

      // ---- bucket keys; Mkey (global max bucket) and BmaxKey ----
      unsigned kj[RSLOTS];
      unsigned lkmax = 0;
#pragma unroll
      for (int j = 0; j < RSLOTS; ++j) {
        kj[j] = (unsigned)(pk[j] >> 32);
        lkmax = (kj[j] > lkmax) ? kj[j] : lkmax;
      }
      const unsigned Mkey    = wave_umax_dpp(lkmax);
      const unsigned BmaxKey = wave_umax_dpp(((lane & 3) == 3) ? lkmax : 0u);

      int cap = N_ANCH - nsel;
      int S = 0;

      if (Mkey > BmaxKey) {
        // -------- typical path: compact live entries (key32 > BmaxKey) -----
        // compacted key layout: key32<<32 | (0xFFFF-idx)<<16 | rank
        // (rank = LDS position of this entry's coords; order unaffected
        //  since idx is unique -> rank never decides a comparison)
        int base = 0;
#pragma unroll
        for (int j = 0; j < RSLOTS; ++j) {
          bool live = kj[j] > BmaxKey;
          ull bal = __ballot(live);
          int rank = base + (int)__popcll(bal & ((1ull << lane) - 1ull));
          if (live) {
            sm.f.lv[rank] = (pk[j] & 0xFFFFFFFF00000000ull)
                          | ((pk[j] & 0xFFFFull) << 16) | (ull)(unsigned)rank;
            int p = 0xFFFF - (int)(pk[j] & 0xFFFFull);
            sm.f.lc[rank][0] = pos[3 * p];
            sm.f.lc[rank][1] = pos[3 * p + 1];
            sm.f.lc[rank][2] = pos[3 * p + 2];
          }
          base += (int)__popcll(bal);
        }
        const int live_n = base;   // wave-uniform, 1..384

        // load compaction data to registers (packed key + f32 coords)
        ull pk2[CCAP]; float c2x[CCAP], c2y[CCAP], c2z[CCAP];
#pragma unroll
        for (int tt = 0; tt < CCAP; ++tt) {
          if (live_n > tt * 64) {
            int e = tt * 64 + lane;
            bool ok = e < live_n;
            ull    v  = sm.f.lv[e];
            float  x  = sm.f.lc[e][0];
            float  y  = sm.f.lc[e][1];
            float  z  = sm.f.lc[e][2];
            pk2[tt] = ok ? v : 0ull;
            c2x[tt] = ok ? x : 0.0f;
            c2y[tt] = ok ? y : 0.0f;
            c2z[tt] = ok ? z : 0.0f;
          } else {
            pk2[tt] = 0ull;
            c2x[tt] = 0.0f; c2y[tt] = 0.0f; c2z[tt] = 0.0f;
          }
        }

        // ---- S-loop: zero-ballot zero-readlane chain; md inline (R4) ----
#pragma unroll 1
        while (S < cap) {
          // in-lane max over 6 packed keys
          ull wpk = pk2[0];
#pragma unroll
          for (int tt = 1; tt < CCAP; ++tt)
            wpk = (pk2[tt] > wpk) ? pk2[tt] : wpk;

          // phase 1: wave max of value key (hi32)
          unsigned hi = (unsigned)(wpk >> 32);
          unsigned M  = wave_umax_dpp(hi);
          if (S != 0 && !(M > BmaxKey)) break;
          // phase 2: among value-max holders, max lo32 = (idx-asc, rank)
          unsigned lo = (hi == M) ? (unsigned)wpk : 0u;
          unsigned L  = wave_umax_dpp(lo);
          ull full = ((ull)M << 32) | (ull)L;
          int widx = 0xFFFF - (int)((L >> 16) & 0xFFFFu);
          int rank = (int)(L & 0xFFFFu);
          float wx = sm.f.lc[rank][0];    // broadcast LDS read (no conflict)
          float wy = sm.f.lc[rank][1];
          float wz = sm.f.lc[rank][2];
          if (gw == 0 && lane == 0) ST_RLX(anchors + nsel + S, widx);

          // update packed keys: u64 min vs new-anchor distance key (low32
          // preserved: idx+rank). Winner dies (-> 0); dead slots stay 0.
#pragma unroll
          for (int tt = 0; tt < CCAP; ++tt) {
            if (live_n > tt * 64) {
              float d = dist32(c2x[tt], c2y[tt], c2z[tt], wx, wy, wz);
              ull dpk = ((ull)key32f(d) << 32) | (pk2[tt] & 0xFFFFFFFFull);
              ull nv  = (dpk < pk2[tt]) ? dpk : pk2[tt];
              pk2[tt] = (pk2[tt] == full) ? 0ull : nv;
            }
          }
          // inline apply to own md slice (bubble-filler under the chain)
#pragma unroll
          for (int k2 = 0; k2 < PPT; ++k2)
            md[k2] = fminf(md[k2], dist32(pdx[k2], pdy[k2], pdz[k2], wx, wy, wz));
          S++;
        }
      } else {
        // -------- fallback (bucket tie at Bmax; rare): packed-exact loop ----
        // operates on raw pool words {key32|idx16}; exact u64 butterfly.
#pragma unroll 1
        while (S < cap) {
          ull wpk = pk[0];
#pragma unroll
          for (int j = 1; j < RSLOTS; ++j) wpk = (pk[j] > wpk) ? pk[j] : wpk;
          ull g = wpk;
#pragma unroll
          for (int off = 1; off < 64; off <<= 1) {
            ull o = __shfl_xor(g, off);
            g = (o > g) ? o : g;
          }
          unsigned wkey = (unsigned)(g >> 32);
          if (S != 0 && !(wkey > BmaxKey)) break;
          int widx = 0xFFFF - (int)(g & 0xFFFFull);
          if (widx < 0) widx = 0;                      // sentinel clamp
          if (widx >= N_PTS) widx = N_PTS - 1;
          float wx = pos[3 * widx];
          float wy = pos[3 * widx + 1];
          float wz = pos[3 * widx + 2];
          if (gw == 0 && lane == 0) ST_RLX(anchors + nsel + S, widx);
#pragma unroll
          for (int j = 0; j < RSLOTS; ++j) {
            int p = 0xFFFF - (int)(pk[j] & 0xFFFFull);
            if (p < 0) p = 0;
            if (p >= N_PTS) p = N_PTS - 1;
            float d = dist32(pos[3 * p], pos[3 * p + 1], pos[3 * p + 2], wx, wy, wz);
            ull dpk = ((ull)key32f(d) << 32) | (pk[j] & 0xFFFFull);
            ull nv  = (dpk < pk[j]) ? dpk : pk[j];
            pk[j] = (pk[j] == g) ? 0ull : nv;
          }
#pragma unroll
          for (int k2 = 0; k2 < PPT; ++k2)
            md[k2] = fminf(md[k2], dist32(pdx[k2], pdy[k2], pdz[k2], wx, wy, wz));
          S++;
        }
      }
      nsel += S;

      // refresh thread-local argmax
      bv = -3.3e38f; bi = 0x7fffffff;
#pragma unroll
      for (int k = 0; k < PPT; ++k) {
        int i = gtid + k * STRIDE;
        bool bt = (md[k] > bv) || (md[k] == bv && i < bi);
        bv = bt ? md[k] : bv; bi = bt ? i : bi;
      }
    }
  } else {
    // =============== KNN: one wave per anchor (no barriers) ===============
    const int aidx = blockIdx.x - NFB;
    int a = -1;
    for (;;) {
      if (lane == 0) a = LD_RLX(anchors + aidx);
      a = __shfl(a, 0);
      if (a >= 0) break;
      __builtin_amdgcn_s_sleep(32);
    }
    const int ai = a;
    const float ax = pos[3 * ai], ay = pos[3 * ai + 1], az = pos[3 * ai + 2];

    // per-lane top-20 (u64 keys, static indexing ONLY -> stays in VGPRs)
    ull key[KNN];
#pragma unroll
    for (int s = 0; s < KNN; ++s) key[s] = ~0ull;
    ull kmax = ~0ull; int smax = 0;
#pragma unroll 1
    for (int k = 0; k < N_PTS / 64; ++k) {   // 625 candidates per lane, exact
      int j = (k << 6) + lane;
      float dx = pos[3 * j] - ax, dy = pos[3 * j + 1] - ay, dz = pos[3 * j + 2] - az;
      float d  = dx * dx + dy * dy + dz * dz;
      ull nk = ((ull)__float_as_uint(d) << 32) | (unsigned)j;
      if (nk < kmax) {
#pragma unroll
        for (int s = 0; s < KNN; ++s) key[s] = (s == smax) ? nk : key[s];
        kmax = 0ull; smax = 0;
#pragma unroll
        for (int s = 0; s < KNN; ++s) {
          bool g = key[s] > kmax;
          kmax = g ? key[s] : kmax;
          smax = g ? s : smax;
        }
      }
    }

    // wave-wide merge: 20 extract-min rounds (shuffle butterfly, no LDS sync)
    ull lmin = ~0ull; int ls = 0;
#pragma unroll
    for (int s = 0; s < KNN; ++s) {
      bool l = key[s] < lmin;
      lmin = l ? key[s] : lmin; ls = l ? s : ls;
    }
#pragma unroll 1
    for (int r = 0; r < KNN; ++r) {
      ull g = lmin;
#pragma unroll
      for (int off = 1; off < 64; off <<= 1) {
        ull ov = __shfl_xor(g, off);
        g = (ov < g) ? ov : g;
      }
      if (lane == 0) sm.k.w[r] = (int)(g & 0xffffffffull);
      if (lmin == g) {          // unique owner consumes & rescans (all static)
#pragma unroll
        for (int s = 0; s < KNN; ++s) key[s] = (s == ls) ? ~0ull : key[s];
        lmin = ~0ull; ls = 0;
#pragma unroll
        for (int s = 0; s < KNN; ++s) {
          bool l = key[s] < lmin;
          lmin = l ? key[s] : lmin; ls = l ? s : ls;
        }
      }
    }

    if (lane == 0) {
      double mx = 0, my = 0, mz = 0;
      for (int r = 0; r < KNN; ++r) {
        int p = sm.k.w[r];
        mx += (double)pos[3 * p]; my += (double)pos[3 * p + 1]; mz += (double)pos[3 * p + 2];
      }
      mx /= KNN; my /= KNN; mz /= KNN;
      double xx = 0, xy = 0, xz = 0, yy = 0, yz = 0, zz = 0;
      for (int r = 0; r < KNN; ++r) {
        int p = sm.k.w[r];
        double cx = (double)pos[3 * p]     - mx;
        double cy = (double)pos[3 * p + 1] - my;
        double cz = (double)pos[3 * p + 2] - mz;
        xx += cx * cx; xy += cx * cy; xz += cx * cz;
        yy += cy * cy; yz += cy * cz; zz += cz * cz;
      }
      double v0, v1, v2;
      eig3_maxvec(xx, xy, xz, yy, yz, zz, v0, v1, v2);

      double a0 = vec_pred[3 * aidx], a1 = vec_pred[3 * aidx + 1], a2 = vec_pred[3 * aidx + 2];
      double an = sqrt(a0 * a0 + a1 * a1 + a2 * a2);
      double bn = sqrt(v0 * v0 + v1 * v1 + v2 * v2);
      double denom = fmax(an, 1e-8) * fmax(bn, 1e-8);
      double c = fabs((a0 * v0 + a1 * v1 + a2 * v2) / denom);
      atomicAdd(acc, log(c + 1e-6));
    }
  }
}

__global__ void finalize_kernel(const double* __restrict__ acc, float* __restrict__ out) {
  out[0] = (float)(-acc[0] / (double)N_ANCH);
}

// ===========================================================================
extern "C" void kernel_launch(void* const* d_in, const int* in_sizes, int n_in,
                              void* d_out, int out_size, void* d_ws, size_t ws_size,
                              hipStream_t stream) {
  (void)in_sizes; (void)n_in; (void)out_size; (void)ws_size;
  const float* vec_pred = (const float*)d_in[0];
  const float* pos      = (const float*)d_in[1];
  float* out = (float*)d_out;

  char* ws = (char*)d_ws;
  double* acc     = (double*)(ws + 0);
  int*    flag    = (int*)(ws + 64);
  ull*    slots   = (ull*)(ws + 1024);
  int*    anchors = (int*)(ws + 17408);

  hipMemsetAsync(ws, 0, 1024, stream);                   // acc + flags
  hipMemsetAsync(ws + 17408, 0xFF, N_ANCH * 4, stream);  // anchors = -1
  hipLaunchKernelGGL(fps_knn_kernel, dim3(NFB + N_ANCH), dim3(BT), 0, stream,
                     pos, vec_pred, flag, slots, anchors, acc);
  hipLaunchKernelGGL(finalize_kernel, dim3(1), dim3(1), 0, stream, acc, out);
}